// Round 8
// baseline (534.615 us; speedup 1.0000x reference)
//
#include <hip/hip_runtime.h>
#include <stdint.h>

// ---------------------------------------------------------------------------
// MambaLikeBlock on MI355X (gfx950)
// R14: B-from-L2. Six K-loop scheduling variants (R8-R13) all landed at the
//     same ~6200-cyc per-block-iter wall cost; accounting shows the CU's
//     LDS port at its measured ~85 B/cyc ceiling (128 ds_read_b128 + 64KB
//     gload_lds writes per CU iter-period) while MFMA=20%, HBM=13% idle.
//     Fix is structural, not scheduling: the B operand is a 1-2MB
//     L2-resident weight -> read B fragments DIRECTLY from global into
//     registers (contiguous 64B/row lines, L1/L2-served). Removes half the
//     ds_reads, half the LDS writes, half the gload_lds. A-staging keeps
//     the R11-proven full-drain 2-buffer at 4 blocks/CU (LDS 34KB).
//     Scans/LN/prep unchanged from R12/R13.
// ---------------------------------------------------------------------------

#define L_SEQ 32768
#define CDIM 512
#define LN_EPS 1e-5f
#define CHUNK 64
#define NCHUNK (L_SEQ / CHUNK) // 512
#define NGRP 16
#define GCHUNK (NCHUNK / NGRP) // 32

typedef __attribute__((ext_vector_type(8))) short short8;
typedef __attribute__((ext_vector_type(4))) float floatx4;

__device__ inline unsigned short f2bf(float f) {
  union { float f; unsigned int u; } v; v.f = f;
  unsigned int r = v.u + 0x7fffu + ((v.u >> 16) & 1u);
  return (unsigned short)(r >> 16);
}
__device__ inline float bf2f(unsigned short h) {
  union { float f; unsigned int u; } v; v.u = ((unsigned int)h) << 16;
  return v.f;
}
__device__ inline float sigmoidf_(float x) { return 1.0f / (1.0f + __expf(-x)); }

// dT^e for e in [0,31], 5 square-and-multiply steps
__device__ inline float powi5(float s, int e) {
  float p = 1.f;
#pragma unroll
  for (int b = 0; b < 5; b++) { if (e & (1 << b)) p *= s; s *= s; }
  return p;
}

// global -> LDS direct copy, 16B per lane.
__device__ __forceinline__ void gll16(const void* g, void* l) {
  __builtin_amdgcn_global_load_lds(
      (__attribute__((address_space(1))) void*)g,
      (__attribute__((address_space(3))) void*)l, 16, 0, 0);
}

// ---------------- LayerNorm: one wave per row (C=512 = 64 lanes x 8) -------
__global__ __launch_bounds__(256) void ln_kernel(const float* __restrict__ x,
    const float* __restrict__ w, const float* __restrict__ b,
    unsigned short* __restrict__ out) {
  int row = blockIdx.x * 4 + (threadIdx.x >> 6);
  int lane = threadIdx.x & 63;
  const float4* xr = (const float4*)(x + (size_t)row * CDIM);
  float4 v0 = xr[lane * 2];
  float4 v1 = xr[lane * 2 + 1];
  float s = v0.x + v0.y + v0.z + v0.w + v1.x + v1.y + v1.z + v1.w;
  float s2 = v0.x * v0.x + v0.y * v0.y + v0.z * v0.z + v0.w * v0.w +
             v1.x * v1.x + v1.y * v1.y + v1.z * v1.z + v1.w * v1.w;
  for (int m = 32; m > 0; m >>= 1) {
    s += __shfl_xor(s, m, 64);
    s2 += __shfl_xor(s2, m, 64);
  }
  float mean = s * (1.0f / CDIM);
  float var = s2 * (1.0f / CDIM) - mean * mean;
  float rs = rsqrtf(var + LN_EPS);
  const float4* wr = (const float4*)w;
  const float4* br = (const float4*)b;
  float4 w0 = wr[lane * 2], w1 = wr[lane * 2 + 1];
  float4 b0 = br[lane * 2], b1 = br[lane * 2 + 1];
  unsigned int p0 = (unsigned int)f2bf((v0.x - mean) * rs * w0.x + b0.x) |
                    ((unsigned int)f2bf((v0.y - mean) * rs * w0.y + b0.y) << 16);
  unsigned int p1 = (unsigned int)f2bf((v0.z - mean) * rs * w0.z + b0.z) |
                    ((unsigned int)f2bf((v0.w - mean) * rs * w0.w + b0.w) << 16);
  unsigned int p2 = (unsigned int)f2bf((v1.x - mean) * rs * w1.x + b1.x) |
                    ((unsigned int)f2bf((v1.y - mean) * rs * w1.y + b1.y) << 16);
  unsigned int p3 = (unsigned int)f2bf((v1.z - mean) * rs * w1.z + b1.z) |
                    ((unsigned int)f2bf((v1.w - mean) * rs * w1.w + b1.w) << 16);
  uint4 pk; pk.x = p0; pk.y = p1; pk.z = p2; pk.w = p3;
  *((uint4*)(out + (size_t)row * CDIM + lane * 8)) = pk;
}

// ---------------- Combined prep: 5 weight transposes + decay (1 launch) ----
__global__ __launch_bounds__(256) void prep_all(
    const float* __restrict__ W_in, const float* __restrict__ W_gate,
    const float* __restrict__ W_out, const float* __restrict__ W_ff1,
    const float* __restrict__ W_ff2, const float* __restrict__ logit,
    unsigned short* __restrict__ Wt_ig, unsigned short* __restrict__ Wt_out,
    unsigned short* __restrict__ Wt_ff1, unsigned short* __restrict__ Wt_ff2,
    float* __restrict__ decay, float* __restrict__ decayT) {
  int b = blockIdx.x;
  if (b >= 1792) { // decay prep
    for (int c = threadIdx.x; c < CDIM; c += 256) {
      float d = sigmoidf_(logit[c]);
      decay[c] = d;
      float p = d;
      for (int i = 0; i < 6; i++) p *= p; // d^64
      decayT[c] = p;
    }
    return;
  }
  const float* W; unsigned short* Wt; int Kd, Nd, t;
  if (b < 256)       { W = W_in;   Wt = Wt_ig;             Kd = 512;  Nd = 512;  t = b; }
  else if (b < 512)  { W = W_gate; Wt = Wt_ig + 512 * 512; Kd = 512;  Nd = 512;  t = b - 256; }
  else if (b < 768)  { W = W_out;  Wt = Wt_out;            Kd = 512;  Nd = 512;  t = b - 512; }
  else if (b < 1280) { W = W_ff1;  Wt = Wt_ff1;            Kd = 512;  Nd = 1024; t = b - 768; }
  else               { W = W_ff2;  Wt = Wt_ff2;            Kd = 1024; Nd = 512;  t = b - 1280; }
  int ntx = Nd >> 5;
  int n0 = (t % ntx) * 32, k0 = (t / ntx) * 32;
  __shared__ float tile[32][33];
  int tx = threadIdx.x & 31, ty = threadIdx.x >> 5; // 32x8
  for (int r = 0; r < 32; r += 8)
    tile[ty + r][tx] = W[(size_t)(k0 + ty + r) * Nd + n0 + tx];
  __syncthreads();
  for (int r = 0; r < 32; r += 8)
    Wt[(size_t)(n0 + ty + r) * Kd + k0 + tx] = f2bf(tile[tx][ty + r]);
}

// ---------------- bf16 MFMA GEMM: C = A(MxK) * Bt(NxK)^T + epilogue --------
// 128x128 tile, 256 threads = 4 waves (2x2), per-wave 64x64 out (4x4 frags).
// BK=32. A: LDS double-buffer (2 x 8KB) via global_load_lds, full-drain
// barrier per iter (R11-proven). B: read fragments DIRECTLY from global
// (weights are L2-resident; per row 4 lanes x 16B = one 64B line).
// 4 blocks/CU. Halves LDS port traffic vs R11 (the measured bottleneck).
template <int EPI>
__global__ __launch_bounds__(256, 4) void gemm_bt(
    const unsigned short* __restrict__ A, const unsigned short* __restrict__ Bt,
    const float* __restrict__ biasA, const float* __restrict__ biasB,
    const float* __restrict__ res, float* __restrict__ outF,
    unsigned short* __restrict__ outU, unsigned short* __restrict__ outG,
    int M, int N, int K) {
  // 34 KB shared: A staging (16 KB) aliased with bf16 epilogue tile.
  __shared__ char smemRaw[34048];
  unsigned short* As = (unsigned short*)smemRaw;  // 2 bufs x 4096 elems

  int nbx = gridDim.x, nby = gridDim.y;
  int bid = blockIdx.x + blockIdx.y * nbx;
  int per = (nbx * nby) >> 3;
  int w = (bid & 7) * per + (bid >> 3);
  int ni = w % nby;
  int mi = w / nby;
  int bm = mi << 7, bn = ni << 7;

  int tid = threadIdx.x, wave = tid >> 6, lane = tid & 63;
  int wm = (wave >> 1) * 64, wn = (wave & 1) * 64;

  // A staging addressing (R6-verified swizzled layout; measured 0 conflicts)
  int srow = wave * 16 + (lane >> 2);
  int chunkSel = (lane & 3) ^ ((lane >> 3) & 3);
  int scol = chunkSel * 8;
  const unsigned short* aP0 = A + (size_t)(bm + srow) * K + scol;
  const unsigned short* aP1 = A + (size_t)(bm + 64 + srow) * K + scol;
  int wbase = wave * 512; // wave-uniform LDS elem offset; HW adds lane*16B

#define STAGEA(bufOff, ktile) do {                                \
    int _o = (ktile) * 32;                                        \
    gll16(aP0 + _o, As + (bufOff) + wbase);                       \
    gll16(aP1 + _o, As + (bufOff) + 2048 + wbase);                \
  } while (0)

  floatx4 acc[4][4];
#pragma unroll
  for (int i = 0; i < 4; i++)
#pragma unroll
    for (int j = 0; j < 4; j++) acc[i][j] = (floatx4){0.f, 0.f, 0.f, 0.f};

  int quad = lane >> 4, r16 = lane & 15;
  int cSwz = ((quad ^ (r16 >> 1)) & 3) * 8; // inverse of A staging swizzle

  // B fragment row pointers: lane reads 16B of row (bn+wn+j*16+r16) at
  // k-elem (k*32 + quad*8). Net layout identical to the old LDS dewizzle.
  const unsigned short* bRow0 = Bt + (size_t)(bn + wn + r16) * K + quad * 8;
  const unsigned short* bRow1 = bRow0 + (size_t)16 * K;
  const unsigned short* bRow2 = bRow0 + (size_t)32 * K;
  const unsigned short* bRow3 = bRow0 + (size_t)48 * K;

  int NK = K >> 5;

  // prologue: A tile 0 -> buf0
  STAGEA(0, 0);
  asm volatile("s_waitcnt vmcnt(0)" ::: "memory");
  __syncthreads();

  for (int k = 0; k < NK; ++k) {
    int cur = (k & 1) * 4096, nxt = cur ^ 4096;
    // B frags for this iter: direct global (L1/L2-served)
    short8 bfm[4];
    int bo = k * 32;
    bfm[0] = *(const short8*)(bRow0 + bo);
    bfm[1] = *(const short8*)(bRow1 + bo);
    bfm[2] = *(const short8*)(bRow2 + bo);
    bfm[3] = *(const short8*)(bRow3 + bo);
    if (k + 1 < NK) STAGEA(nxt, k + 1);  // prefetch next A tile
    short8 af[4];
#pragma unroll
    for (int i = 0; i < 4; i++)
      af[i] = *(const short8*)(&As[cur + (wm + i * 16 + r16) * 32 + cSwz]);
#pragma unroll
    for (int i = 0; i < 4; i++)
#pragma unroll
      for (int j = 0; j < 4; j++)
        acc[i][j] = __builtin_amdgcn_mfma_f32_16x16x32_bf16(af[i], bfm[j], acc[i][j], 0, 0, 0);
    asm volatile("s_waitcnt vmcnt(0)" ::: "memory");
    __syncthreads();
  }
#undef STAGEA

  if (EPI == 1) {
    // fp32 output: 16 lanes x 4B = 64B aligned segments, direct stores
#pragma unroll
    for (int j = 0; j < 4; j++) {
      int n = bn + wn + j * 16 + r16;
#pragma unroll
      for (int i = 0; i < 4; i++) {
        int mb = bm + wm + i * 16 + quad * 4;
#pragma unroll
        for (int r = 0; r < 4; r++) {
          size_t idx = (size_t)(mb + r) * N + n;
          outF[idx] = res[idx] + acc[i][j][r] + biasA[n];
        }
      }
    }
  } else {
    // bf16 output: stage tile in LDS, then coalesced 16B/lane stores
    unsigned short* sm = (unsigned short*)smemRaw;
#pragma unroll
    for (int j = 0; j < 4; j++) {
      int n = bn + wn + j * 16 + r16;
      int ln = wn + j * 16 + r16;
#pragma unroll
      for (int i = 0; i < 4; i++) {
        int lmb = wm + i * 16 + quad * 4;
#pragma unroll
        for (int r = 0; r < 4; r++) {
          float v = acc[i][j][r];
          float t;
          if (EPI == 0) {
            t = (n < 512) ? (v + biasA[n]) : sigmoidf_(v + biasB[n - 512]);
          } else { // EPI == 2
            float z = v + biasA[n];
            t = z * sigmoidf_(z);
          }
          sm[(lmb + r) * 132 + ln] = f2bf(t);
        }
      }
    }
    __syncthreads();
    int row = tid >> 1, half = tid & 1;
    const unsigned short* src = sm + row * 132 + half * 64;
    unsigned short* gptr;
    if (EPI == 0) {
      gptr = ((bn < 512) ? outU : (outG - 512)) + (size_t)(bm + row) * 512 + bn + half * 64;
    } else {
      gptr = outG + (size_t)(bm + row) * N + bn + half * 64;
    }
#pragma unroll
    for (int s = 0; s < 8; s++)
      *(short8*)(gptr + s * 8) = *(const short8*)(src + s * 8);
  }
}

// ---------------- Scan phase 1: per-chunk fwd/bwd aggregates ---------------
__global__ __launch_bounds__(512) void scan_phase1(const unsigned short* __restrict__ u,
    const float* __restrict__ decay, float* __restrict__ fa, float* __restrict__ ba) {
  int c = threadIdx.x, k = blockIdx.x;
  float d = decay[c];
  const unsigned short* up = u + (size_t)k * CHUNK * CDIM + c;
  float f = 0.f, bs = 0.f, p = 1.f;
#pragma unroll 8
  for (int t = 0; t < CHUNK; t++) {
    float v = bf2f(up[(size_t)t * CDIM]);
    f = d * f + v;
    bs += p * v;
    p *= d;
  }
  fa[(size_t)k * CDIM + c] = f;
  ba[(size_t)k * CDIM + c] = bs;
}

// ---------------- Scan phase 2a: group-local carries + group aggregates ----
__global__ __launch_bounds__(512) void scan_p2a(const float* __restrict__ fa,
    const float* __restrict__ ba, const float* __restrict__ decayT,
    float* __restrict__ fc, float* __restrict__ bc,
    float* __restrict__ gaF, float* __restrict__ gaB) {
  int c = threadIdx.x, g = blockIdx.x;
  float dT = decayT[c];
  int k0 = g * GCHUNK;
  float runf = 0.f;
#pragma unroll 4
  for (int j = 0; j < GCHUNK; j++) {
    size_t idx = (size_t)(k0 + j) * CDIM + c;
    fc[idx] = runf;
    runf = dT * runf + fa[idx];
  }
  gaF[(size_t)g * CDIM + c] = runf;
  float runb = 0.f;
#pragma unroll 4
  for (int j = GCHUNK - 1; j >= 0; j--) {
    size_t idx = (size_t)(k0 + j) * CDIM + c;
    bc[idx] = runb;
    runb = dT * runb + ba[idx];
  }
  gaB[(size_t)g * CDIM + c] = runb;
}

// ---------------- Scan phase 2b: 16-step group recurrence ------------------
__global__ __launch_bounds__(512) void scan_p2b(const float* __restrict__ gaF,
    const float* __restrict__ gaB, const float* __restrict__ decayT,
    float* __restrict__ GF, float* __restrict__ GB) {
  int c = threadIdx.x;
  float dT = decayT[c];
  float d32 = dT;
#pragma unroll
  for (int i = 0; i < 5; i++) d32 *= d32;  // dT^32
  float gf = 0.f;
#pragma unroll
  for (int g = 0; g < NGRP; g++) {
    GF[(size_t)g * CDIM + c] = gf;
    gf = d32 * gf + gaF[(size_t)g * CDIM + c];
  }
  float gb = 0.f;
#pragma unroll
  for (int g = NGRP - 1; g >= 0; g--) {
    GB[(size_t)g * CDIM + c] = gb;
    gb = d32 * gb + gaB[(size_t)g * CDIM + c];
  }
}

// ---------------- Scan phase 3: apply carries, combine, gate ---------------
__global__ __launch_bounds__(512) void scan_phase3(const unsigned short* __restrict__ u,
    const unsigned short* __restrict__ gate, const float* __restrict__ decay,
    const float* __restrict__ decayT, const float* __restrict__ fc,
    const float* __restrict__ bc, const float* __restrict__ GF,
    const float* __restrict__ GB, unsigned short* __restrict__ state) {
  int c = threadIdx.x, k = blockIdx.x;
  int g = k >> 5, j = k & 31;
  float d = decay[c];
  float dT = decayT[c];
  size_t base = (size_t)k * CHUNK * CDIM + c;
  size_t kc = (size_t)k * CDIM + c;
  size_t gc = (size_t)g * CDIM + c;
  float run  = fc[kc] + powi5(dT, j) * GF[gc];
  float runb0 = bc[kc] + powi5(dT, 31 - j) * GB[gc];
  float fwd[CHUNK];
  unsigned int us[CHUNK / 2];
#pragma unroll
  for (int t = 0; t < CHUNK; t++) {
    unsigned short uv = u[base + (size_t)t * CDIM];
    if (t & 1) us[t >> 1] |= ((unsigned int)uv) << 16;
    else       us[t >> 1] = uv;
    run = d * run + bf2f(uv);
    fwd[t] = run;
  }
  float runb = runb0;
#pragma unroll
  for (int t = CHUNK - 1; t >= 0; t--) {
    unsigned short uv = (unsigned short)((us[t >> 1] >> ((t & 1) * 16)) & 0xffffu);
    runb = d * runb + bf2f(uv);
    float gv = bf2f(gate[base + (size_t)t * CDIM]);
    state[base + (size_t)t * CDIM] = f2bf(0.5f * (fwd[t] + runb) * gv);
  }
}

// ---------------------------------------------------------------------------
extern "C" void kernel_launch(void* const* d_in, const int* in_sizes, int n_in,
                              void* d_out, int out_size, void* d_ws, size_t ws_size,
                              hipStream_t stream) {
  const float* x = (const float*)d_in[0];
  const float* ln1_w = (const float*)d_in[1];
  const float* ln1_b = (const float*)d_in[2];
  const float* W_in = (const float*)d_in[3];
  const float* b_in = (const float*)d_in[4];
  const float* W_gate = (const float*)d_in[5];
  const float* b_gate = (const float*)d_in[6];
  const float* W_out = (const float*)d_in[7];
  const float* b_out = (const float*)d_in[8];
  const float* decay_logit = (const float*)d_in[9];
  const float* ln2_w = (const float*)d_in[10];
  const float* ln2_b = (const float*)d_in[11];
  const float* W_ff1 = (const float*)d_in[12];
  const float* b_ff1 = (const float*)d_in[13];
  const float* W_ff2 = (const float*)d_in[14];
  const float* b_ff2 = (const float*)d_in[15];

  char* ws = (char*)d_ws;
  size_t off = 0;
  auto alloc = [&](size_t bytes) -> void* {
    void* p = ws + off;
    off += (bytes + 255) & ~(size_t)255;
    return p;
  };
  // --- small persistent buffers ---
  unsigned short* Wt_ig  = (unsigned short*)alloc((size_t)1024 * 512 * 2);
  unsigned short* Wt_out = (unsigned short*)alloc((size_t)512 * 512 * 2);
  unsigned short* Wt_ff1 = (unsigned short*)alloc((size_t)1024 * 512 * 2);
  unsigned short* Wt_ff2 = (unsigned short*)alloc((size_t)512 * 1024 * 2);
  float* fa = (float*)alloc((size_t)NCHUNK * CDIM * 4);
  float* ba = (float*)alloc((size_t)NCHUNK * CDIM * 4);
  float* fc = (float*)alloc((size_t)NCHUNK * CDIM * 4);
  float* bc = (float*)alloc((size_t)NCHUNK * CDIM * 4);
  float* gaF = (float*)alloc((size_t)NGRP * CDIM * 4);
  float* gaB = (float*)alloc((size_t)NGRP * CDIM * 4);
  float* GFb = (float*)alloc((size_t)NGRP * CDIM * 4);
  float* GBb = (float*)alloc((size_t)NGRP * CDIM * 4);
  float* decay  = (float*)alloc(CDIM * 4);
  float* decayT = (float*)alloc(CDIM * 4);
  // --- large aliased regions (liveness-disjoint) ---
  const size_t LC2 = (size_t)L_SEQ * CDIM * 2; // 33.55 MB
  unsigned short* R1 = (unsigned short*)alloc(LC2);      // hidden -> state -> hbuf
  unsigned short* R2 = (unsigned short*)alloc(LC2);      // u(bf16) -> ffb[0:]
  unsigned short* R3 = (unsigned short*)alloc(LC2);      // gate    -> ffb[L*C:]
  unsigned short* hidden = R1;
  unsigned short* state  = R1;
  unsigned short* hbuf   = R1;
  unsigned short* u_buf  = R2;
  unsigned short* gate   = R3;
  unsigned short* ffb    = R2; // 67 MB spanning R2+R3 (contiguous)
  float* x2 = (float*)d_out;   // d_out doubles as x2 buffer

  // single prep launch: all transposes + decay
  prep_all<<<1793, 256, 0, stream>>>(W_in, W_gate, W_out, W_ff1, W_ff2,
      decay_logit, Wt_ig, Wt_out, Wt_ff1, Wt_ff2, decay, decayT);

  // LN1
  ln_kernel<<<L_SEQ / 4, 256, 0, stream>>>(x, ln1_w, ln1_b, hidden);

  // u | gate fused GEMM (N=1024); grid = (M/128, N/128)
  gemm_bt<0><<<dim3(L_SEQ / 128, 1024 / 128), 256, 0, stream>>>(
      hidden, Wt_ig, b_in, b_gate, nullptr, nullptr, u_buf, gate, L_SEQ, 1024, 512);

  // bidirectional scan (hierarchical)
  scan_phase1<<<NCHUNK, 512, 0, stream>>>(u_buf, decay, fa, ba);
  scan_p2a<<<NGRP, 512, 0, stream>>>(fa, ba, decayT, fc, bc, gaF, gaB);
  scan_p2b<<<1, 512, 0, stream>>>(gaF, gaB, decayT, GFb, GBb);
  scan_phase3<<<NCHUNK, 512, 0, stream>>>(u_buf, gate, decay, decayT, fc, bc,
      GFb, GBb, state);

  // x2 = x + state @ W_out + b_out   (written to d_out)
  gemm_bt<1><<<dim3(L_SEQ / 128, 512 / 128), 256, 0, stream>>>(
      state, Wt_out, b_out, nullptr, x, x2, nullptr, nullptr, L_SEQ, 512, 512);

  // LN2
  ln_kernel<<<L_SEQ / 4, 256, 0, stream>>>(x2, ln2_w, ln2_b, hbuf);

  // ff = silu(h @ W_ff1 + b_ff1)
  gemm_bt<2><<<dim3(L_SEQ / 128, 1024 / 128), 256, 0, stream>>>(
      hbuf, Wt_ff1, b_ff1, nullptr, nullptr, nullptr, nullptr, ffb, L_SEQ, 1024, 512);

  // out = x2 + ff @ W_ff2 + b_ff2   (in-place read/write on d_out is per-element safe)
  gemm_bt<1><<<dim3(L_SEQ / 128, 512 / 128), 256, 0, stream>>>(
      ffb, Wt_ff2, b_ff2, nullptr, x2, x2, nullptr, nullptr, L_SEQ, 512, 1024);
}

// Round 9
// 529.897 us; speedup vs baseline: 1.0089x; 1.0089x over previous
//
#include <hip/hip_runtime.h>
#include <stdint.h>

// ---------------------------------------------------------------------------
// MambaLikeBlock on MI355X (gfx950)
// R15: B-in-registers with 1-iteration PREFETCH (R14's B-direct was consumed
//     same-iter -> exposed L2 latency -> regression; the LDS-traffic cut was
//     never actually tested). A-staging returns to the best-measured R11
//     2-buffer full-drain gload_lds at 4 blocks/CU (34KB LDS). B frags load
//     at iter k for k+1; the end-of-iter vmcnt(0) drain guarantees them
//     complete before use -> zero exposed latency, half the LDS-port
//     traffic (the R13 accounting: ds_read+gload_lds writes ~= 85B/cyc
//     ceiling). Also: scan_phase1 fused into gemm0's epilogue (u-tile is
//     already staged in LDS; 256 thr x (chunk,channel) column scans),
//     deleting a 64MB-read dispatch. Scans/LN/prep otherwise R12/R13.
// ---------------------------------------------------------------------------

#define L_SEQ 32768
#define CDIM 512
#define LN_EPS 1e-5f
#define CHUNK 64
#define NCHUNK (L_SEQ / CHUNK) // 512
#define NGRP 16
#define GCHUNK (NCHUNK / NGRP) // 32

typedef __attribute__((ext_vector_type(8))) short short8;
typedef __attribute__((ext_vector_type(4))) float floatx4;

__device__ inline unsigned short f2bf(float f) {
  union { float f; unsigned int u; } v; v.f = f;
  unsigned int r = v.u + 0x7fffu + ((v.u >> 16) & 1u);
  return (unsigned short)(r >> 16);
}
__device__ inline float bf2f(unsigned short h) {
  union { float f; unsigned int u; } v; v.u = ((unsigned int)h) << 16;
  return v.f;
}
__device__ inline float sigmoidf_(float x) { return 1.0f / (1.0f + __expf(-x)); }

// dT^e for e in [0,31], 5 square-and-multiply steps
__device__ inline float powi5(float s, int e) {
  float p = 1.f;
#pragma unroll
  for (int b = 0; b < 5; b++) { if (e & (1 << b)) p *= s; s *= s; }
  return p;
}

// global -> LDS direct copy, 16B per lane.
__device__ __forceinline__ void gll16(const void* g, void* l) {
  __builtin_amdgcn_global_load_lds(
      (__attribute__((address_space(1))) void*)g,
      (__attribute__((address_space(3))) void*)l, 16, 0, 0);
}

// ---------------- LayerNorm: one wave per row (C=512 = 64 lanes x 8) -------
__global__ __launch_bounds__(256) void ln_kernel(const float* __restrict__ x,
    const float* __restrict__ w, const float* __restrict__ b,
    unsigned short* __restrict__ out) {
  int row = blockIdx.x * 4 + (threadIdx.x >> 6);
  int lane = threadIdx.x & 63;
  const float4* xr = (const float4*)(x + (size_t)row * CDIM);
  float4 v0 = xr[lane * 2];
  float4 v1 = xr[lane * 2 + 1];
  float s = v0.x + v0.y + v0.z + v0.w + v1.x + v1.y + v1.z + v1.w;
  float s2 = v0.x * v0.x + v0.y * v0.y + v0.z * v0.z + v0.w * v0.w +
             v1.x * v1.x + v1.y * v1.y + v1.z * v1.z + v1.w * v1.w;
  for (int m = 32; m > 0; m >>= 1) {
    s += __shfl_xor(s, m, 64);
    s2 += __shfl_xor(s2, m, 64);
  }
  float mean = s * (1.0f / CDIM);
  float var = s2 * (1.0f / CDIM) - mean * mean;
  float rs = rsqrtf(var + LN_EPS);
  const float4* wr = (const float4*)w;
  const float4* br = (const float4*)b;
  float4 w0 = wr[lane * 2], w1 = wr[lane * 2 + 1];
  float4 b0 = br[lane * 2], b1 = br[lane * 2 + 1];
  unsigned int p0 = (unsigned int)f2bf((v0.x - mean) * rs * w0.x + b0.x) |
                    ((unsigned int)f2bf((v0.y - mean) * rs * w0.y + b0.y) << 16);
  unsigned int p1 = (unsigned int)f2bf((v0.z - mean) * rs * w0.z + b0.z) |
                    ((unsigned int)f2bf((v0.w - mean) * rs * w0.w + b0.w) << 16);
  unsigned int p2 = (unsigned int)f2bf((v1.x - mean) * rs * w1.x + b1.x) |
                    ((unsigned int)f2bf((v1.y - mean) * rs * w1.y + b1.y) << 16);
  unsigned int p3 = (unsigned int)f2bf((v1.z - mean) * rs * w1.z + b1.z) |
                    ((unsigned int)f2bf((v1.w - mean) * rs * w1.w + b1.w) << 16);
  uint4 pk; pk.x = p0; pk.y = p1; pk.z = p2; pk.w = p3;
  *((uint4*)(out + (size_t)row * CDIM + lane * 8)) = pk;
}

// ---------------- Combined prep: 5 weight transposes + decay (1 launch) ----
__global__ __launch_bounds__(256) void prep_all(
    const float* __restrict__ W_in, const float* __restrict__ W_gate,
    const float* __restrict__ W_out, const float* __restrict__ W_ff1,
    const float* __restrict__ W_ff2, const float* __restrict__ logit,
    unsigned short* __restrict__ Wt_ig, unsigned short* __restrict__ Wt_out,
    unsigned short* __restrict__ Wt_ff1, unsigned short* __restrict__ Wt_ff2,
    float* __restrict__ decay, float* __restrict__ decayT) {
  int b = blockIdx.x;
  if (b >= 1792) { // decay prep
    for (int c = threadIdx.x; c < CDIM; c += 256) {
      float d = sigmoidf_(logit[c]);
      decay[c] = d;
      float p = d;
      for (int i = 0; i < 6; i++) p *= p; // d^64
      decayT[c] = p;
    }
    return;
  }
  const float* W; unsigned short* Wt; int Kd, Nd, t;
  if (b < 256)       { W = W_in;   Wt = Wt_ig;             Kd = 512;  Nd = 512;  t = b; }
  else if (b < 512)  { W = W_gate; Wt = Wt_ig + 512 * 512; Kd = 512;  Nd = 512;  t = b - 256; }
  else if (b < 768)  { W = W_out;  Wt = Wt_out;            Kd = 512;  Nd = 512;  t = b - 512; }
  else if (b < 1280) { W = W_ff1;  Wt = Wt_ff1;            Kd = 512;  Nd = 1024; t = b - 768; }
  else               { W = W_ff2;  Wt = Wt_ff2;            Kd = 1024; Nd = 512;  t = b - 1280; }
  int ntx = Nd >> 5;
  int n0 = (t % ntx) * 32, k0 = (t / ntx) * 32;
  __shared__ float tile[32][33];
  int tx = threadIdx.x & 31, ty = threadIdx.x >> 5; // 32x8
  for (int r = 0; r < 32; r += 8)
    tile[ty + r][tx] = W[(size_t)(k0 + ty + r) * Nd + n0 + tx];
  __syncthreads();
  for (int r = 0; r < 32; r += 8)
    Wt[(size_t)(n0 + ty + r) * Kd + k0 + tx] = f2bf(tile[tx][ty + r]);
}

// ---------------- bf16 MFMA GEMM: C = A(MxK) * Bt(NxK)^T + epilogue --------
// 128x128 tile, 256 threads = 4 waves (2x2), per-wave 64x64 out (4x4 frags).
// BK=32. A: LDS 2-buffer via global_load_lds, full-drain per iter
// (R11-proven best). B: registers, prefetched ONE ITERATION AHEAD from
// global (L2-resident weights; the drain guarantees completion).
// 4 blocks/CU; LDS-port traffic halved vs R11.
// EPI 0: n<512 -> outU = v+biasA (bf16) + FUSED per-chunk scan aggregates
//        (fa/ba) from the staged LDS tile; n>=512 -> outG = sigmoid(v+biasB)
// EPI 1: outF = res + v + biasA[n]           (float out, direct stores)
// EPI 2: outG = bf16(silu(v + biasA[n]))     (bf16 out, staged)
template <int EPI>
__global__ __launch_bounds__(256, 4) void gemm_bt(
    const unsigned short* __restrict__ A, const unsigned short* __restrict__ Bt,
    const float* __restrict__ biasA, const float* __restrict__ biasB,
    const float* __restrict__ res, float* __restrict__ outF,
    unsigned short* __restrict__ outU, unsigned short* __restrict__ outG,
    const float* __restrict__ decayP, float* __restrict__ faP,
    float* __restrict__ baP, int M, int N, int K) {
  // 34 KB shared: A staging (16 KB) aliased with bf16 epilogue tile.
  __shared__ char smemRaw[34048];
  unsigned short* As = (unsigned short*)smemRaw;  // 2 bufs x 4096 elems

  int nbx = gridDim.x, nby = gridDim.y;
  int bid = blockIdx.x + blockIdx.y * nbx;
  int per = (nbx * nby) >> 3;
  int w = (bid & 7) * per + (bid >> 3);
  int ni = w % nby;
  int mi = w / nby;
  int bm = mi << 7, bn = ni << 7;

  int tid = threadIdx.x, wave = tid >> 6, lane = tid & 63;
  int wm = (wave >> 1) * 64, wn = (wave & 1) * 64;

  // A staging addressing (R6-verified swizzled layout; measured 0 conflicts)
  int srow = wave * 16 + (lane >> 2);
  int chunkSel = (lane & 3) ^ ((lane >> 3) & 3);
  int scol = chunkSel * 8;
  const unsigned short* aP0 = A + (size_t)(bm + srow) * K + scol;
  const unsigned short* aP1 = A + (size_t)(bm + 64 + srow) * K + scol;
  int wbase = wave * 512; // wave-uniform LDS elem offset; HW adds lane*16B

#define STAGEA(bufOff, ktile) do {                                \
    int _o = (ktile) * 32;                                        \
    gll16(aP0 + _o, As + (bufOff) + wbase);                       \
    gll16(aP1 + _o, As + (bufOff) + 2048 + wbase);                \
  } while (0)

  floatx4 acc[4][4];
#pragma unroll
  for (int i = 0; i < 4; i++)
#pragma unroll
    for (int j = 0; j < 4; j++) acc[i][j] = (floatx4){0.f, 0.f, 0.f, 0.f};

  int quad = lane >> 4, r16 = lane & 15;
  int cSwz = ((quad ^ (r16 >> 1)) & 3) * 8; // inverse of A staging swizzle

  // B fragment row pointers (R14-verified layout): lane (r16,quad) reads 16B
  // of row (bn+wn+j*16+r16) at k-elems [k*32+quad*8, +8).
  const unsigned short* bRow0 = Bt + (size_t)(bn + wn + r16) * K + quad * 8;
  const unsigned short* bRow1 = bRow0 + (size_t)16 * K;
  const unsigned short* bRow2 = bRow0 + (size_t)32 * K;
  const unsigned short* bRow3 = bRow0 + (size_t)48 * K;

  int NK = K >> 5;

  // prologue: A tile 0 -> buf0; B frags for k=0 -> regs
  short8 bcur0 = *(const short8*)(bRow0);
  short8 bcur1 = *(const short8*)(bRow1);
  short8 bcur2 = *(const short8*)(bRow2);
  short8 bcur3 = *(const short8*)(bRow3);
  STAGEA(0, 0);
  asm volatile("s_waitcnt vmcnt(0)" ::: "memory");
  __syncthreads();

  for (int k = 0; k < NK; ++k) {
    int cur = (k & 1) * 4096, nxt = cur ^ 4096;
    short8 bnx0, bnx1, bnx2, bnx3;
    if (k + 1 < NK) {
      int bo = (k + 1) * 32;
      bnx0 = *(const short8*)(bRow0 + bo);   // prefetch B for k+1 (regs)
      bnx1 = *(const short8*)(bRow1 + bo);
      bnx2 = *(const short8*)(bRow2 + bo);
      bnx3 = *(const short8*)(bRow3 + bo);
      STAGEA(nxt, k + 1);                    // prefetch A for k+1 (LDS)
    }
    short8 af[4];
#pragma unroll
    for (int i = 0; i < 4; i++)
      af[i] = *(const short8*)(&As[cur + (wm + i * 16 + r16) * 32 + cSwz]);
#pragma unroll
    for (int i = 0; i < 4; i++) {
      acc[i][0] = __builtin_amdgcn_mfma_f32_16x16x32_bf16(af[i], bcur0, acc[i][0], 0, 0, 0);
      acc[i][1] = __builtin_amdgcn_mfma_f32_16x16x32_bf16(af[i], bcur1, acc[i][1], 0, 0, 0);
      acc[i][2] = __builtin_amdgcn_mfma_f32_16x16x32_bf16(af[i], bcur2, acc[i][2], 0, 0, 0);
      acc[i][3] = __builtin_amdgcn_mfma_f32_16x16x32_bf16(af[i], bcur3, acc[i][3], 0, 0, 0);
    }
    // drain: A(k+1) staged + B(k+1) regs complete; protects cur buf too.
    asm volatile("s_waitcnt vmcnt(0)" ::: "memory");
    __syncthreads();
    bcur0 = bnx0; bcur1 = bnx1; bcur2 = bnx2; bcur3 = bnx3;
  }
#undef STAGEA

  if (EPI == 1) {
    // fp32 output: 16 lanes x 4B = 64B aligned segments, direct stores
#pragma unroll
    for (int j = 0; j < 4; j++) {
      int n = bn + wn + j * 16 + r16;
#pragma unroll
      for (int i = 0; i < 4; i++) {
        int mb = bm + wm + i * 16 + quad * 4;
#pragma unroll
        for (int r = 0; r < 4; r++) {
          size_t idx = (size_t)(mb + r) * N + n;
          outF[idx] = res[idx] + acc[i][j][r] + biasA[n];
        }
      }
    }
  } else {
    // bf16 output: stage tile in LDS, then coalesced 16B/lane stores
    unsigned short* sm = (unsigned short*)smemRaw;
#pragma unroll
    for (int j = 0; j < 4; j++) {
      int n = bn + wn + j * 16 + r16;
      int ln = wn + j * 16 + r16;
#pragma unroll
      for (int i = 0; i < 4; i++) {
        int lmb = wm + i * 16 + quad * 4;
#pragma unroll
        for (int r = 0; r < 4; r++) {
          float v = acc[i][j][r];
          float t;
          if (EPI == 0) {
            t = (n < 512) ? (v + biasA[n]) : sigmoidf_(v + biasB[n - 512]);
          } else { // EPI == 2
            float z = v + biasA[n];
            t = z * sigmoidf_(z);
          }
          sm[(lmb + r) * 132 + ln] = f2bf(t);
        }
      }
    }
    __syncthreads();
    int row = tid >> 1, half = tid & 1;
    const unsigned short* src = sm + row * 132 + half * 64;
    unsigned short* gptr;
    if (EPI == 0) {
      gptr = ((bn < 512) ? outU : (outG - 512)) + (size_t)(bm + row) * 512 + bn + half * 64;
    } else {
      gptr = outG + (size_t)(bm + row) * N + bn + half * 64;
    }
#pragma unroll
    for (int s = 0; s < 8; s++)
      *(short8*)(gptr + s * 8) = *(const short8*)(src + s * 8);

    // ---- fused scan_phase1 (EPI 0, u-half blocks only) ----
    // The staged sm tile IS bf16(u) for rows bm..bm+128 (= chunks 2mi,2mi+1)
    // x channels bn..bn+128. 256 threads: one (chunk,channel) column each;
    // numerics identical to the standalone phase1 (bf16 u input).
    if (EPI == 0 && bn < 512 && faP != nullptr) {
      int cl = tid & 127;          // channel within block
      int ch = tid >> 7;           // chunk half (0/1)
      int cg = bn + cl;            // global channel
      float d = decayP[cg];
      const unsigned short* col = sm + (ch * 64) * 132 + cl;
      float f = 0.f, bs = 0.f, p = 1.f;
#pragma unroll 8
      for (int t = 0; t < CHUNK; t++) {
        float v = bf2f(col[t * 132]);
        f = d * f + v;
        bs += p * v;
        p *= d;
      }
      size_t kidx = (size_t)((bm >> 6) + ch) * CDIM + cg;
      faP[kidx] = f;
      baP[kidx] = bs;
    }
  }
}

// ---------------- Scan phase 2a: group-local carries + group aggregates ----
__global__ __launch_bounds__(512) void scan_p2a(const float* __restrict__ fa,
    const float* __restrict__ ba, const float* __restrict__ decayT,
    float* __restrict__ fc, float* __restrict__ bc,
    float* __restrict__ gaF, float* __restrict__ gaB) {
  int c = threadIdx.x, g = blockIdx.x;
  float dT = decayT[c];
  int k0 = g * GCHUNK;
  float runf = 0.f;
#pragma unroll 4
  for (int j = 0; j < GCHUNK; j++) {
    size_t idx = (size_t)(k0 + j) * CDIM + c;
    fc[idx] = runf;
    runf = dT * runf + fa[idx];
  }
  gaF[(size_t)g * CDIM + c] = runf;
  float runb = 0.f;
#pragma unroll 4
  for (int j = GCHUNK - 1; j >= 0; j--) {
    size_t idx = (size_t)(k0 + j) * CDIM + c;
    bc[idx] = runb;
    runb = dT * runb + ba[idx];
  }
  gaB[(size_t)g * CDIM + c] = runb;
}

// ---------------- Scan phase 2b: 16-step group recurrence ------------------
__global__ __launch_bounds__(512) void scan_p2b(const float* __restrict__ gaF,
    const float* __restrict__ gaB, const float* __restrict__ decayT,
    float* __restrict__ GF, float* __restrict__ GB) {
  int c = threadIdx.x;
  float dT = decayT[c];
  float d32 = dT;
#pragma unroll
  for (int i = 0; i < 5; i++) d32 *= d32;  // dT^32
  float gf = 0.f;
#pragma unroll
  for (int g = 0; g < NGRP; g++) {
    GF[(size_t)g * CDIM + c] = gf;
    gf = d32 * gf + gaF[(size_t)g * CDIM + c];
  }
  float gb = 0.f;
#pragma unroll
  for (int g = NGRP - 1; g >= 0; g--) {
    GB[(size_t)g * CDIM + c] = gb;
    gb = d32 * gb + gaB[(size_t)g * CDIM + c];
  }
}

// ---------------- Scan phase 3: apply carries, combine, gate ---------------
__global__ __launch_bounds__(512) void scan_phase3(const unsigned short* __restrict__ u,
    const unsigned short* __restrict__ gate, const float* __restrict__ decay,
    const float* __restrict__ decayT, const float* __restrict__ fc,
    const float* __restrict__ bc, const float* __restrict__ GF,
    const float* __restrict__ GB, unsigned short* __restrict__ state) {
  int c = threadIdx.x, k = blockIdx.x;
  int g = k >> 5, j = k & 31;
  float d = decay[c];
  float dT = decayT[c];
  size_t base = (size_t)k * CHUNK * CDIM + c;
  size_t kc = (size_t)k * CDIM + c;
  size_t gc = (size_t)g * CDIM + c;
  float run  = fc[kc] + powi5(dT, j) * GF[gc];
  float runb0 = bc[kc] + powi5(dT, 31 - j) * GB[gc];
  float fwd[CHUNK];
  unsigned int us[CHUNK / 2];
#pragma unroll
  for (int t = 0; t < CHUNK; t++) {
    unsigned short uv = u[base + (size_t)t * CDIM];
    if (t & 1) us[t >> 1] |= ((unsigned int)uv) << 16;
    else       us[t >> 1] = uv;
    run = d * run + bf2f(uv);
    fwd[t] = run;
  }
  float runb = runb0;
#pragma unroll
  for (int t = CHUNK - 1; t >= 0; t--) {
    unsigned short uv = (unsigned short)((us[t >> 1] >> ((t & 1) * 16)) & 0xffffu);
    runb = d * runb + bf2f(uv);
    float gv = bf2f(gate[base + (size_t)t * CDIM]);
    state[base + (size_t)t * CDIM] = f2bf(0.5f * (fwd[t] + runb) * gv);
  }
}

// ---------------------------------------------------------------------------
extern "C" void kernel_launch(void* const* d_in, const int* in_sizes, int n_in,
                              void* d_out, int out_size, void* d_ws, size_t ws_size,
                              hipStream_t stream) {
  const float* x = (const float*)d_in[0];
  const float* ln1_w = (const float*)d_in[1];
  const float* ln1_b = (const float*)d_in[2];
  const float* W_in = (const float*)d_in[3];
  const float* b_in = (const float*)d_in[4];
  const float* W_gate = (const float*)d_in[5];
  const float* b_gate = (const float*)d_in[6];
  const float* W_out = (const float*)d_in[7];
  const float* b_out = (const float*)d_in[8];
  const float* decay_logit = (const float*)d_in[9];
  const float* ln2_w = (const float*)d_in[10];
  const float* ln2_b = (const float*)d_in[11];
  const float* W_ff1 = (const float*)d_in[12];
  const float* b_ff1 = (const float*)d_in[13];
  const float* W_ff2 = (const float*)d_in[14];
  const float* b_ff2 = (const float*)d_in[15];

  char* ws = (char*)d_ws;
  size_t off = 0;
  auto alloc = [&](size_t bytes) -> void* {
    void* p = ws + off;
    off += (bytes + 255) & ~(size_t)255;
    return p;
  };
  // --- small persistent buffers ---
  unsigned short* Wt_ig  = (unsigned short*)alloc((size_t)1024 * 512 * 2);
  unsigned short* Wt_out = (unsigned short*)alloc((size_t)512 * 512 * 2);
  unsigned short* Wt_ff1 = (unsigned short*)alloc((size_t)1024 * 512 * 2);
  unsigned short* Wt_ff2 = (unsigned short*)alloc((size_t)512 * 1024 * 2);
  float* fa = (float*)alloc((size_t)NCHUNK * CDIM * 4);
  float* ba = (float*)alloc((size_t)NCHUNK * CDIM * 4);
  float* fc = (float*)alloc((size_t)NCHUNK * CDIM * 4);
  float* bc = (float*)alloc((size_t)NCHUNK * CDIM * 4);
  float* gaF = (float*)alloc((size_t)NGRP * CDIM * 4);
  float* gaB = (float*)alloc((size_t)NGRP * CDIM * 4);
  float* GFb = (float*)alloc((size_t)NGRP * CDIM * 4);
  float* GBb = (float*)alloc((size_t)NGRP * CDIM * 4);
  float* decay  = (float*)alloc(CDIM * 4);
  float* decayT = (float*)alloc(CDIM * 4);
  // --- large aliased regions (liveness-disjoint) ---
  const size_t LC2 = (size_t)L_SEQ * CDIM * 2; // 33.55 MB
  unsigned short* R1 = (unsigned short*)alloc(LC2);      // hidden -> state -> hbuf
  unsigned short* R2 = (unsigned short*)alloc(LC2);      // u(bf16) -> ffb[0:]
  unsigned short* R3 = (unsigned short*)alloc(LC2);      // gate    -> ffb[L*C:]
  unsigned short* hidden = R1;
  unsigned short* state  = R1;
  unsigned short* hbuf   = R1;
  unsigned short* u_buf  = R2;
  unsigned short* gate   = R3;
  unsigned short* ffb    = R2; // 67 MB spanning R2+R3 (contiguous)
  float* x2 = (float*)d_out;   // d_out doubles as x2 buffer

  // single prep launch: all transposes + decay
  prep_all<<<1793, 256, 0, stream>>>(W_in, W_gate, W_out, W_ff1, W_ff2,
      decay_logit, Wt_ig, Wt_out, Wt_ff1, Wt_ff2, decay, decayT);

  // LN1
  ln_kernel<<<L_SEQ / 4, 256, 0, stream>>>(x, ln1_w, ln1_b, hidden);

  // u | gate fused GEMM (N=1024) with fused phase1 aggregates
  gemm_bt<0><<<dim3(L_SEQ / 128, 1024 / 128), 256, 0, stream>>>(
      hidden, Wt_ig, b_in, b_gate, nullptr, nullptr, u_buf, gate,
      decay, fa, ba, L_SEQ, 1024, 512);

  // bidirectional scan (hierarchical; phase1 fused above)
  scan_p2a<<<NGRP, 512, 0, stream>>>(fa, ba, decayT, fc, bc, gaF, gaB);
  scan_p2b<<<1, 512, 0, stream>>>(gaF, gaB, decayT, GFb, GBb);
  scan_phase3<<<NCHUNK, 512, 0, stream>>>(u_buf, gate, decay, decayT, fc, bc,
      GFb, GBb, state);

  // x2 = x + state @ W_out + b_out   (written to d_out)
  gemm_bt<1><<<dim3(L_SEQ / 128, 512 / 128), 256, 0, stream>>>(
      state, Wt_out, b_out, nullptr, x, x2, nullptr, nullptr,
      nullptr, nullptr, nullptr, L_SEQ, 512, 512);

  // LN2
  ln_kernel<<<L_SEQ / 4, 256, 0, stream>>>(x2, ln2_w, ln2_b, hbuf);

  // ff = silu(h @ W_ff1 + b_ff1)
  gemm_bt<2><<<dim3(L_SEQ / 128, 1024 / 128), 256, 0, stream>>>(
      hbuf, Wt_ff1, b_ff1, nullptr, nullptr, nullptr, nullptr, ffb,
      nullptr, nullptr, nullptr, L_SEQ, 1024, 512);

  // out = x2 + ff @ W_ff2 + b_ff2   (in-place read/write on d_out is per-element safe)
  gemm_bt<1><<<dim3(L_SEQ / 128, 512 / 128), 256, 0, stream>>>(
      ffb, Wt_ff2, b_ff2, nullptr, x2, x2, nullptr, nullptr,
      nullptr, nullptr, nullptr, L_SEQ, 512, 1024);
}

// Round 10
// 424.790 us; speedup vs baseline: 1.2585x; 1.2474x over previous
//
#include <hip/hip_runtime.h>
#include <stdint.h>

// ---------------------------------------------------------------------------
// MambaLikeBlock on MI355X (gfx950)
// R16: recombine best-measured components. R14/R15 proved B-from-global is
//     worse than B-through-LDS even with latency fully hidden (113 vs 79.6us)
//     AND that halving LDS-port traffic gains nothing -> LDS-port theory and
//     B-latency theory both dead; R11's all-gload_lds full-drain 2-buffer at
//     4 blocks/CU is the empirical optimum of 8 K-loop variants. This round:
//     exact R11 K-loop revert + keep R15's verified phase1-fusion in gemm0's
//     epilogue (deletes the 14us standalone dispatch) + R12 hierarchical
//     scan. K-loop surgery is closed per pre-commitment.
// ---------------------------------------------------------------------------

#define L_SEQ 32768
#define CDIM 512
#define LN_EPS 1e-5f
#define CHUNK 64
#define NCHUNK (L_SEQ / CHUNK) // 512
#define NGRP 16
#define GCHUNK (NCHUNK / NGRP) // 32

typedef __attribute__((ext_vector_type(8))) short short8;
typedef __attribute__((ext_vector_type(4))) float floatx4;

__device__ inline unsigned short f2bf(float f) {
  union { float f; unsigned int u; } v; v.f = f;
  unsigned int r = v.u + 0x7fffu + ((v.u >> 16) & 1u);
  return (unsigned short)(r >> 16);
}
__device__ inline float bf2f(unsigned short h) {
  union { float f; unsigned int u; } v; v.u = ((unsigned int)h) << 16;
  return v.f;
}
__device__ inline float sigmoidf_(float x) { return 1.0f / (1.0f + __expf(-x)); }

// dT^e for e in [0,31], 5 square-and-multiply steps
__device__ inline float powi5(float s, int e) {
  float p = 1.f;
#pragma unroll
  for (int b = 0; b < 5; b++) { if (e & (1 << b)) p *= s; s *= s; }
  return p;
}

// global -> LDS direct copy, 16B per lane.
__device__ __forceinline__ void gll16(const void* g, void* l) {
  __builtin_amdgcn_global_load_lds(
      (__attribute__((address_space(1))) void*)g,
      (__attribute__((address_space(3))) void*)l, 16, 0, 0);
}

// ---------------- LayerNorm: one wave per row (C=512 = 64 lanes x 8) -------
__global__ __launch_bounds__(256) void ln_kernel(const float* __restrict__ x,
    const float* __restrict__ w, const float* __restrict__ b,
    unsigned short* __restrict__ out) {
  int row = blockIdx.x * 4 + (threadIdx.x >> 6);
  int lane = threadIdx.x & 63;
  const float4* xr = (const float4*)(x + (size_t)row * CDIM);
  float4 v0 = xr[lane * 2];
  float4 v1 = xr[lane * 2 + 1];
  float s = v0.x + v0.y + v0.z + v0.w + v1.x + v1.y + v1.z + v1.w;
  float s2 = v0.x * v0.x + v0.y * v0.y + v0.z * v0.z + v0.w * v0.w +
             v1.x * v1.x + v1.y * v1.y + v1.z * v1.z + v1.w * v1.w;
  for (int m = 32; m > 0; m >>= 1) {
    s += __shfl_xor(s, m, 64);
    s2 += __shfl_xor(s2, m, 64);
  }
  float mean = s * (1.0f / CDIM);
  float var = s2 * (1.0f / CDIM) - mean * mean;
  float rs = rsqrtf(var + LN_EPS);
  const float4* wr = (const float4*)w;
  const float4* br = (const float4*)b;
  float4 w0 = wr[lane * 2], w1 = wr[lane * 2 + 1];
  float4 b0 = br[lane * 2], b1 = br[lane * 2 + 1];
  unsigned int p0 = (unsigned int)f2bf((v0.x - mean) * rs * w0.x + b0.x) |
                    ((unsigned int)f2bf((v0.y - mean) * rs * w0.y + b0.y) << 16);
  unsigned int p1 = (unsigned int)f2bf((v0.z - mean) * rs * w0.z + b0.z) |
                    ((unsigned int)f2bf((v0.w - mean) * rs * w0.w + b0.w) << 16);
  unsigned int p2 = (unsigned int)f2bf((v1.x - mean) * rs * w1.x + b1.x) |
                    ((unsigned int)f2bf((v1.y - mean) * rs * w1.y + b1.y) << 16);
  unsigned int p3 = (unsigned int)f2bf((v1.z - mean) * rs * w1.z + b1.z) |
                    ((unsigned int)f2bf((v1.w - mean) * rs * w1.w + b1.w) << 16);
  uint4 pk; pk.x = p0; pk.y = p1; pk.z = p2; pk.w = p3;
  *((uint4*)(out + (size_t)row * CDIM + lane * 8)) = pk;
}

// ---------------- Combined prep: 5 weight transposes + decay (1 launch) ----
__global__ __launch_bounds__(256) void prep_all(
    const float* __restrict__ W_in, const float* __restrict__ W_gate,
    const float* __restrict__ W_out, const float* __restrict__ W_ff1,
    const float* __restrict__ W_ff2, const float* __restrict__ logit,
    unsigned short* __restrict__ Wt_ig, unsigned short* __restrict__ Wt_out,
    unsigned short* __restrict__ Wt_ff1, unsigned short* __restrict__ Wt_ff2,
    float* __restrict__ decay, float* __restrict__ decayT) {
  int b = blockIdx.x;
  if (b >= 1792) { // decay prep
    for (int c = threadIdx.x; c < CDIM; c += 256) {
      float d = sigmoidf_(logit[c]);
      decay[c] = d;
      float p = d;
      for (int i = 0; i < 6; i++) p *= p; // d^64
      decayT[c] = p;
    }
    return;
  }
  const float* W; unsigned short* Wt; int Kd, Nd, t;
  if (b < 256)       { W = W_in;   Wt = Wt_ig;             Kd = 512;  Nd = 512;  t = b; }
  else if (b < 512)  { W = W_gate; Wt = Wt_ig + 512 * 512; Kd = 512;  Nd = 512;  t = b - 256; }
  else if (b < 768)  { W = W_out;  Wt = Wt_out;            Kd = 512;  Nd = 512;  t = b - 512; }
  else if (b < 1280) { W = W_ff1;  Wt = Wt_ff1;            Kd = 512;  Nd = 1024; t = b - 768; }
  else               { W = W_ff2;  Wt = Wt_ff2;            Kd = 1024; Nd = 512;  t = b - 1280; }
  int ntx = Nd >> 5;
  int n0 = (t % ntx) * 32, k0 = (t / ntx) * 32;
  __shared__ float tile[32][33];
  int tx = threadIdx.x & 31, ty = threadIdx.x >> 5; // 32x8
  for (int r = 0; r < 32; r += 8)
    tile[ty + r][tx] = W[(size_t)(k0 + ty + r) * Nd + n0 + tx];
  __syncthreads();
  for (int r = 0; r < 32; r += 8)
    Wt[(size_t)(n0 + ty + r) * Kd + k0 + tx] = f2bf(tile[tx][ty + r]);
}

// ---------------- bf16 MFMA GEMM: C = A(MxK) * Bt(NxK)^T + epilogue --------
// 128x128 tile, 256 threads = 4 waves (2x2), per-wave 64x64 out (4x4 frags).
// BK=32. A+B: LDS 2-buffer via global_load_lds, full-drain barrier per iter
// (R11 config, empirical optimum of 8 variants: 79.6us @ N=1024).
// 4 blocks/CU.
// EPI 0: n<512 -> outU = v+biasA (bf16) + FUSED per-chunk scan aggregates
//        (fa/ba) from the staged LDS tile; n>=512 -> outG = sigmoid(v+biasB)
// EPI 1: outF = res + v + biasA[n]           (float out, direct stores)
// EPI 2: outG = bf16(silu(v + biasA[n]))     (bf16 out, staged)
template <int EPI>
__global__ __launch_bounds__(256, 4) void gemm_bt(
    const unsigned short* __restrict__ A, const unsigned short* __restrict__ Bt,
    const float* __restrict__ biasA, const float* __restrict__ biasB,
    const float* __restrict__ res, float* __restrict__ outF,
    unsigned short* __restrict__ outU, unsigned short* __restrict__ outG,
    const float* __restrict__ decayP, float* __restrict__ faP,
    float* __restrict__ baP, int M, int N, int K) {
  // 34 KB shared: K-loop staging (32 KB) aliased with bf16 epilogue tile.
  __shared__ char smemRaw[34048];
  unsigned short* As = (unsigned short*)smemRaw;            // 2 bufs x 4096 elems
  unsigned short* Bs = (unsigned short*)(smemRaw + 16384);  // 2 bufs x 4096 elems

  // XCD-aware remap: grid = (M/128, N/128); XCD = bid % 8.
  int nbx = gridDim.x, nby = gridDim.y;
  int bid = blockIdx.x + blockIdx.y * nbx;
  int per = (nbx * nby) >> 3;
  int w = (bid & 7) * per + (bid >> 3);
  int ni = w % nby;
  int mi = w / nby;
  int bm = mi << 7, bn = ni << 7;

  int tid = threadIdx.x, wave = tid >> 6, lane = tid & 63;
  int wm = (wave >> 1) * 64, wn = (wave & 1) * 64;

  // staging addressing (R6-verified swizzled layout; measured 0 conflicts)
  int srow = wave * 16 + (lane >> 2);
  int chunkSel = (lane & 3) ^ ((lane >> 3) & 3);
  int scol = chunkSel * 8;
  const unsigned short* aP0 = A + (size_t)(bm + srow) * K + scol;
  const unsigned short* aP1 = A + (size_t)(bm + 64 + srow) * K + scol;
  const unsigned short* bP0 = Bt + (size_t)(bn + srow) * K + scol;
  const unsigned short* bP1 = Bt + (size_t)(bn + 64 + srow) * K + scol;
  int wbase = wave * 512; // wave-uniform LDS elem offset; HW adds lane*16B

#define STAGE(bufOff, ktile) do {                                 \
    int _o = (ktile) * 32;                                        \
    gll16(aP0 + _o, As + (bufOff) + wbase);                       \
    gll16(aP1 + _o, As + (bufOff) + 2048 + wbase);                \
    gll16(bP0 + _o, Bs + (bufOff) + wbase);                       \
    gll16(bP1 + _o, Bs + (bufOff) + 2048 + wbase);                \
  } while (0)

  floatx4 acc[4][4];
#pragma unroll
  for (int i = 0; i < 4; i++)
#pragma unroll
    for (int j = 0; j < 4; j++) acc[i][j] = (floatx4){0.f, 0.f, 0.f, 0.f};

  int quad = lane >> 4, r16 = lane & 15;
  int cSwz = ((quad ^ (r16 >> 1)) & 3) * 8; // inverse of staging swizzle

  int NK = K >> 5;

  // prologue: tile 0 -> buf0
  STAGE(0, 0);
  asm volatile("s_waitcnt vmcnt(0)" ::: "memory");
  __syncthreads();

  for (int k = 0; k < NK; ++k) {
    int cur = (k & 1) * 4096, nxt = cur ^ 4096;
    if (k + 1 < NK) STAGE(nxt, k + 1);  // prefetch next tile into other buf
    short8 af[4], bfm[4];
#pragma unroll
    for (int i = 0; i < 4; i++)
      af[i] = *(const short8*)(&As[cur + (wm + i * 16 + r16) * 32 + cSwz]);
#pragma unroll
    for (int j = 0; j < 4; j++)
      bfm[j] = *(const short8*)(&Bs[cur + (wn + j * 16 + r16) * 32 + cSwz]);
#pragma unroll
    for (int i = 0; i < 4; i++)
#pragma unroll
      for (int j = 0; j < 4; j++)
        acc[i][j] = __builtin_amdgcn_mfma_f32_16x16x32_bf16(af[i], bfm[j], acc[i][j], 0, 0, 0);
    asm volatile("s_waitcnt vmcnt(0)" ::: "memory");
    __syncthreads();
  }
#undef STAGE

  if (EPI == 1) {
    // fp32 output: 16 lanes x 4B = 64B aligned segments, direct stores
#pragma unroll
    for (int j = 0; j < 4; j++) {
      int n = bn + wn + j * 16 + r16;
#pragma unroll
      for (int i = 0; i < 4; i++) {
        int mb = bm + wm + i * 16 + quad * 4;
#pragma unroll
        for (int r = 0; r < 4; r++) {
          size_t idx = (size_t)(mb + r) * N + n;
          outF[idx] = res[idx] + acc[i][j][r] + biasA[n];
        }
      }
    }
  } else {
    // bf16 output: stage tile in LDS, then coalesced 16B/lane stores
    unsigned short* sm = (unsigned short*)smemRaw;
#pragma unroll
    for (int j = 0; j < 4; j++) {
      int n = bn + wn + j * 16 + r16;
      int ln = wn + j * 16 + r16;
#pragma unroll
      for (int i = 0; i < 4; i++) {
        int lmb = wm + i * 16 + quad * 4;
#pragma unroll
        for (int r = 0; r < 4; r++) {
          float v = acc[i][j][r];
          float t;
          if (EPI == 0) {
            t = (n < 512) ? (v + biasA[n]) : sigmoidf_(v + biasB[n - 512]);
          } else { // EPI == 2
            float z = v + biasA[n];
            t = z * sigmoidf_(z);
          }
          sm[(lmb + r) * 132 + ln] = f2bf(t);
        }
      }
    }
    __syncthreads();
    int row = tid >> 1, half = tid & 1;
    const unsigned short* src = sm + row * 132 + half * 64;
    unsigned short* gptr;
    if (EPI == 0) {
      gptr = ((bn < 512) ? outU : (outG - 512)) + (size_t)(bm + row) * 512 + bn + half * 64;
    } else {
      gptr = outG + (size_t)(bm + row) * N + bn + half * 64;
    }
#pragma unroll
    for (int s = 0; s < 8; s++)
      *(short8*)(gptr + s * 8) = *(const short8*)(src + s * 8);

    // ---- fused scan_phase1 (EPI 0, u-half blocks only; R15-verified) ----
    // The staged sm tile IS bf16(u) for rows bm..bm+128 (= chunks 2mi,2mi+1)
    // x channels bn..bn+128. 256 threads: one (chunk,channel) column each;
    // numerics identical to the standalone phase1 (bf16 u input).
    if (EPI == 0 && bn < 512 && faP != nullptr) {
      int cl = tid & 127;          // channel within block
      int ch = tid >> 7;           // chunk half (0/1)
      int cg = bn + cl;            // global channel
      float d = decayP[cg];
      const unsigned short* col = sm + (ch * 64) * 132 + cl;
      float f = 0.f, bs = 0.f, p = 1.f;
#pragma unroll 8
      for (int t = 0; t < CHUNK; t++) {
        float v = bf2f(col[t * 132]);
        f = d * f + v;
        bs += p * v;
        p *= d;
      }
      size_t kidx = (size_t)((bm >> 6) + ch) * CDIM + cg;
      faP[kidx] = f;
      baP[kidx] = bs;
    }
  }
}

// ---------------- Scan phase 2a: group-local carries + group aggregates ----
__global__ __launch_bounds__(512) void scan_p2a(const float* __restrict__ fa,
    const float* __restrict__ ba, const float* __restrict__ decayT,
    float* __restrict__ fc, float* __restrict__ bc,
    float* __restrict__ gaF, float* __restrict__ gaB) {
  int c = threadIdx.x, g = blockIdx.x;
  float dT = decayT[c];
  int k0 = g * GCHUNK;
  float runf = 0.f;
#pragma unroll 4
  for (int j = 0; j < GCHUNK; j++) {
    size_t idx = (size_t)(k0 + j) * CDIM + c;
    fc[idx] = runf;
    runf = dT * runf + fa[idx];
  }
  gaF[(size_t)g * CDIM + c] = runf;
  float runb = 0.f;
#pragma unroll 4
  for (int j = GCHUNK - 1; j >= 0; j--) {
    size_t idx = (size_t)(k0 + j) * CDIM + c;
    bc[idx] = runb;
    runb = dT * runb + ba[idx];
  }
  gaB[(size_t)g * CDIM + c] = runb;
}

// ---------------- Scan phase 2b: 16-step group recurrence ------------------
__global__ __launch_bounds__(512) void scan_p2b(const float* __restrict__ gaF,
    const float* __restrict__ gaB, const float* __restrict__ decayT,
    float* __restrict__ GF, float* __restrict__ GB) {
  int c = threadIdx.x;
  float dT = decayT[c];
  float d32 = dT;
#pragma unroll
  for (int i = 0; i < 5; i++) d32 *= d32;  // dT^32
  float gf = 0.f;
#pragma unroll
  for (int g = 0; g < NGRP; g++) {
    GF[(size_t)g * CDIM + c] = gf;
    gf = d32 * gf + gaF[(size_t)g * CDIM + c];
  }
  float gb = 0.f;
#pragma unroll
  for (int g = NGRP - 1; g >= 0; g--) {
    GB[(size_t)g * CDIM + c] = gb;
    gb = d32 * gb + gaB[(size_t)g * CDIM + c];
  }
}

// ---------------- Scan phase 3: apply carries, combine, gate ---------------
__global__ __launch_bounds__(512) void scan_phase3(const unsigned short* __restrict__ u,
    const unsigned short* __restrict__ gate, const float* __restrict__ decay,
    const float* __restrict__ decayT, const float* __restrict__ fc,
    const float* __restrict__ bc, const float* __restrict__ GF,
    const float* __restrict__ GB, unsigned short* __restrict__ state) {
  int c = threadIdx.x, k = blockIdx.x;
  int g = k >> 5, j = k & 31;
  float d = decay[c];
  float dT = decayT[c];
  size_t base = (size_t)k * CHUNK * CDIM + c;
  size_t kc = (size_t)k * CDIM + c;
  size_t gc = (size_t)g * CDIM + c;
  float run  = fc[kc] + powi5(dT, j) * GF[gc];
  float runb0 = bc[kc] + powi5(dT, 31 - j) * GB[gc];
  float fwd[CHUNK];
  unsigned int us[CHUNK / 2];
#pragma unroll
  for (int t = 0; t < CHUNK; t++) {
    unsigned short uv = u[base + (size_t)t * CDIM];
    if (t & 1) us[t >> 1] |= ((unsigned int)uv) << 16;
    else       us[t >> 1] = uv;
    run = d * run + bf2f(uv);
    fwd[t] = run;
  }
  float runb = runb0;
#pragma unroll
  for (int t = CHUNK - 1; t >= 0; t--) {
    unsigned short uv = (unsigned short)((us[t >> 1] >> ((t & 1) * 16)) & 0xffffu);
    runb = d * runb + bf2f(uv);
    float gv = bf2f(gate[base + (size_t)t * CDIM]);
    state[base + (size_t)t * CDIM] = f2bf(0.5f * (fwd[t] + runb) * gv);
  }
}

// ---------------------------------------------------------------------------
extern "C" void kernel_launch(void* const* d_in, const int* in_sizes, int n_in,
                              void* d_out, int out_size, void* d_ws, size_t ws_size,
                              hipStream_t stream) {
  const float* x = (const float*)d_in[0];
  const float* ln1_w = (const float*)d_in[1];
  const float* ln1_b = (const float*)d_in[2];
  const float* W_in = (const float*)d_in[3];
  const float* b_in = (const float*)d_in[4];
  const float* W_gate = (const float*)d_in[5];
  const float* b_gate = (const float*)d_in[6];
  const float* W_out = (const float*)d_in[7];
  const float* b_out = (const float*)d_in[8];
  const float* decay_logit = (const float*)d_in[9];
  const float* ln2_w = (const float*)d_in[10];
  const float* ln2_b = (const float*)d_in[11];
  const float* W_ff1 = (const float*)d_in[12];
  const float* b_ff1 = (const float*)d_in[13];
  const float* W_ff2 = (const float*)d_in[14];
  const float* b_ff2 = (const float*)d_in[15];

  char* ws = (char*)d_ws;
  size_t off = 0;
  auto alloc = [&](size_t bytes) -> void* {
    void* p = ws + off;
    off += (bytes + 255) & ~(size_t)255;
    return p;
  };
  // --- small persistent buffers ---
  unsigned short* Wt_ig  = (unsigned short*)alloc((size_t)1024 * 512 * 2);
  unsigned short* Wt_out = (unsigned short*)alloc((size_t)512 * 512 * 2);
  unsigned short* Wt_ff1 = (unsigned short*)alloc((size_t)1024 * 512 * 2);
  unsigned short* Wt_ff2 = (unsigned short*)alloc((size_t)512 * 1024 * 2);
  float* fa = (float*)alloc((size_t)NCHUNK * CDIM * 4);
  float* ba = (float*)alloc((size_t)NCHUNK * CDIM * 4);
  float* fc = (float*)alloc((size_t)NCHUNK * CDIM * 4);
  float* bc = (float*)alloc((size_t)NCHUNK * CDIM * 4);
  float* gaF = (float*)alloc((size_t)NGRP * CDIM * 4);
  float* gaB = (float*)alloc((size_t)NGRP * CDIM * 4);
  float* GFb = (float*)alloc((size_t)NGRP * CDIM * 4);
  float* GBb = (float*)alloc((size_t)NGRP * CDIM * 4);
  float* decay  = (float*)alloc(CDIM * 4);
  float* decayT = (float*)alloc(CDIM * 4);
  // --- large aliased regions (liveness-disjoint) ---
  const size_t LC2 = (size_t)L_SEQ * CDIM * 2; // 33.55 MB
  unsigned short* R1 = (unsigned short*)alloc(LC2);      // hidden -> state -> hbuf
  unsigned short* R2 = (unsigned short*)alloc(LC2);      // u(bf16) -> ffb[0:]
  unsigned short* R3 = (unsigned short*)alloc(LC2);      // gate    -> ffb[L*C:]
  unsigned short* hidden = R1;
  unsigned short* state  = R1;
  unsigned short* hbuf   = R1;
  unsigned short* u_buf  = R2;
  unsigned short* gate   = R3;
  unsigned short* ffb    = R2; // 67 MB spanning R2+R3 (contiguous)
  float* x2 = (float*)d_out;   // d_out doubles as x2 buffer

  // single prep launch: all transposes + decay
  prep_all<<<1793, 256, 0, stream>>>(W_in, W_gate, W_out, W_ff1, W_ff2,
      decay_logit, Wt_ig, Wt_out, Wt_ff1, Wt_ff2, decay, decayT);

  // LN1
  ln_kernel<<<L_SEQ / 4, 256, 0, stream>>>(x, ln1_w, ln1_b, hidden);

  // u | gate fused GEMM (N=1024) with fused phase1 aggregates
  gemm_bt<0><<<dim3(L_SEQ / 128, 1024 / 128), 256, 0, stream>>>(
      hidden, Wt_ig, b_in, b_gate, nullptr, nullptr, u_buf, gate,
      decay, fa, ba, L_SEQ, 1024, 512);

  // bidirectional scan (hierarchical; phase1 fused above)
  scan_p2a<<<NGRP, 512, 0, stream>>>(fa, ba, decayT, fc, bc, gaF, gaB);
  scan_p2b<<<1, 512, 0, stream>>>(gaF, gaB, decayT, GFb, GBb);
  scan_phase3<<<NCHUNK, 512, 0, stream>>>(u_buf, gate, decay, decayT, fc, bc,
      GFb, GBb, state);

  // x2 = x + state @ W_out + b_out   (written to d_out)
  gemm_bt<1><<<dim3(L_SEQ / 128, 512 / 128), 256, 0, stream>>>(
      state, Wt_out, b_out, nullptr, x, x2, nullptr, nullptr,
      nullptr, nullptr, nullptr, L_SEQ, 512, 512);

  // LN2
  ln_kernel<<<L_SEQ / 4, 256, 0, stream>>>(x2, ln2_w, ln2_b, hbuf);

  // ff = silu(h @ W_ff1 + b_ff1)
  gemm_bt<2><<<dim3(L_SEQ / 128, 1024 / 128), 256, 0, stream>>>(
      hbuf, Wt_ff1, b_ff1, nullptr, nullptr, nullptr, nullptr, ffb,
      nullptr, nullptr, nullptr, L_SEQ, 1024, 512);

  // out = x2 + ff @ W_ff2 + b_ff2   (in-place read/write on d_out is per-element safe)
  gemm_bt<1><<<dim3(L_SEQ / 128, 512 / 128), 256, 0, stream>>>(
      ffb, Wt_ff2, b_ff2, nullptr, x2, x2, nullptr, nullptr,
      nullptr, nullptr, nullptr, L_SEQ, 512, 1024);
}

// Round 11
// 410.978 us; speedup vs baseline: 1.3008x; 1.0336x over previous
//
#include <hip/hip_runtime.h>
#include <stdint.h>

// ---------------------------------------------------------------------------
// MambaLikeBlock on MI355X (gfx950)
// R17: bf16 residual stream. The fp32 x2 path was the largest untouched
//     traffic item: gemm_out wrote 64MB, LN2 read 64MB, ff2 re-read 64MB,
//     all BW-bound. Now: gemm_out (EPI3) emits x2 as bf16 (32MB, staged
//     coalesced), LN2 reads bf16, ff2 (EPI4) reads bf16 residual and
//     writes the final fp32 directly to d_out. Residual precision kept
//     where cheap (gemm_out still reads original fp32 x). Also merged
//     prep_all+LN1 into one launch. GEMM K-loop frozen at R11 optimum
//     (8 variants tested, closed); fused phase1 and hierarchical scan
//     kept from R15/R12.
// ---------------------------------------------------------------------------

#define L_SEQ 32768
#define CDIM 512
#define LN_EPS 1e-5f
#define CHUNK 64
#define NCHUNK (L_SEQ / CHUNK) // 512
#define NGRP 16
#define GCHUNK (NCHUNK / NGRP) // 32

typedef __attribute__((ext_vector_type(8))) short short8;
typedef __attribute__((ext_vector_type(4))) float floatx4;

__device__ inline unsigned short f2bf(float f) {
  union { float f; unsigned int u; } v; v.f = f;
  unsigned int r = v.u + 0x7fffu + ((v.u >> 16) & 1u);
  return (unsigned short)(r >> 16);
}
__device__ inline float bf2f(unsigned short h) {
  union { float f; unsigned int u; } v; v.u = ((unsigned int)h) << 16;
  return v.f;
}
__device__ inline float sigmoidf_(float x) { return 1.0f / (1.0f + __expf(-x)); }

// dT^e for e in [0,31], 5 square-and-multiply steps
__device__ inline float powi5(float s, int e) {
  float p = 1.f;
#pragma unroll
  for (int b = 0; b < 5; b++) { if (e & (1 << b)) p *= s; s *= s; }
  return p;
}

// global -> LDS direct copy, 16B per lane.
__device__ __forceinline__ void gll16(const void* g, void* l) {
  __builtin_amdgcn_global_load_lds(
      (__attribute__((address_space(1))) void*)g,
      (__attribute__((address_space(3))) void*)l, 16, 0, 0);
}

// ---------------- Merged: LN1 (blocks 0..8191) + prep (blocks 8192+) ------
__global__ __launch_bounds__(256) void prep_ln1(
    const float* __restrict__ x, const float* __restrict__ ln1_w,
    const float* __restrict__ ln1_b, unsigned short* __restrict__ out,
    const float* __restrict__ W_in, const float* __restrict__ W_gate,
    const float* __restrict__ W_out, const float* __restrict__ W_ff1,
    const float* __restrict__ W_ff2, const float* __restrict__ logit,
    unsigned short* __restrict__ Wt_ig, unsigned short* __restrict__ Wt_out,
    unsigned short* __restrict__ Wt_ff1, unsigned short* __restrict__ Wt_ff2,
    float* __restrict__ decay, float* __restrict__ decayT) {
  int bx = blockIdx.x;
  if (bx < L_SEQ / 4) {
    // ---- LN1: one wave per row ----
    int row = bx * 4 + (threadIdx.x >> 6);
    int lane = threadIdx.x & 63;
    const float4* xr = (const float4*)(x + (size_t)row * CDIM);
    float4 v0 = xr[lane * 2];
    float4 v1 = xr[lane * 2 + 1];
    float s = v0.x + v0.y + v0.z + v0.w + v1.x + v1.y + v1.z + v1.w;
    float s2 = v0.x * v0.x + v0.y * v0.y + v0.z * v0.z + v0.w * v0.w +
               v1.x * v1.x + v1.y * v1.y + v1.z * v1.z + v1.w * v1.w;
    for (int m = 32; m > 0; m >>= 1) {
      s += __shfl_xor(s, m, 64);
      s2 += __shfl_xor(s2, m, 64);
    }
    float mean = s * (1.0f / CDIM);
    float var = s2 * (1.0f / CDIM) - mean * mean;
    float rs = rsqrtf(var + LN_EPS);
    const float4* wr = (const float4*)ln1_w;
    const float4* br = (const float4*)ln1_b;
    float4 w0 = wr[lane * 2], w1 = wr[lane * 2 + 1];
    float4 b0 = br[lane * 2], b1 = br[lane * 2 + 1];
    unsigned int p0 = (unsigned int)f2bf((v0.x - mean) * rs * w0.x + b0.x) |
                      ((unsigned int)f2bf((v0.y - mean) * rs * w0.y + b0.y) << 16);
    unsigned int p1 = (unsigned int)f2bf((v0.z - mean) * rs * w0.z + b0.z) |
                      ((unsigned int)f2bf((v0.w - mean) * rs * w0.w + b0.w) << 16);
    unsigned int p2 = (unsigned int)f2bf((v1.x - mean) * rs * w1.x + b1.x) |
                      ((unsigned int)f2bf((v1.y - mean) * rs * w1.y + b1.y) << 16);
    unsigned int p3 = (unsigned int)f2bf((v1.z - mean) * rs * w1.z + b1.z) |
                      ((unsigned int)f2bf((v1.w - mean) * rs * w1.w + b1.w) << 16);
    uint4 pk; pk.x = p0; pk.y = p1; pk.z = p2; pk.w = p3;
    *((uint4*)(out + (size_t)row * CDIM + lane * 8)) = pk;
    return;
  }
  int b = bx - L_SEQ / 4;
  if (b >= 1792) { // decay prep
    for (int c = threadIdx.x; c < CDIM; c += 256) {
      float d = sigmoidf_(logit[c]);
      decay[c] = d;
      float p = d;
      for (int i = 0; i < 6; i++) p *= p; // d^64
      decayT[c] = p;
    }
    return;
  }
  const float* W; unsigned short* Wt; int Kd, Nd, t;
  if (b < 256)       { W = W_in;   Wt = Wt_ig;             Kd = 512;  Nd = 512;  t = b; }
  else if (b < 512)  { W = W_gate; Wt = Wt_ig + 512 * 512; Kd = 512;  Nd = 512;  t = b - 256; }
  else if (b < 768)  { W = W_out;  Wt = Wt_out;            Kd = 512;  Nd = 512;  t = b - 512; }
  else if (b < 1280) { W = W_ff1;  Wt = Wt_ff1;            Kd = 512;  Nd = 1024; t = b - 768; }
  else               { W = W_ff2;  Wt = Wt_ff2;            Kd = 1024; Nd = 512;  t = b - 1280; }
  int ntx = Nd >> 5;
  int n0 = (t % ntx) * 32, k0 = (t / ntx) * 32;
  __shared__ float tile[32][33];
  int tx = threadIdx.x & 31, ty = threadIdx.x >> 5; // 32x8
  for (int r = 0; r < 32; r += 8)
    tile[ty + r][tx] = W[(size_t)(k0 + ty + r) * Nd + n0 + tx];
  __syncthreads();
  for (int r = 0; r < 32; r += 8)
    Wt[(size_t)(n0 + ty + r) * Kd + k0 + tx] = f2bf(tile[tx][ty + r]);
}

// ---------------- LN over bf16 input (x2b) ---------------------------------
__global__ __launch_bounds__(256) void ln_bf16(const unsigned short* __restrict__ xb,
    const float* __restrict__ w, const float* __restrict__ b,
    unsigned short* __restrict__ out) {
  int row = blockIdx.x * 4 + (threadIdx.x >> 6);
  int lane = threadIdx.x & 63;
  uint4 uv = *(const uint4*)(xb + (size_t)row * CDIM + lane * 8);
  float v[8];
  v[0] = bf2f((unsigned short)(uv.x & 0xffffu));
  v[1] = bf2f((unsigned short)(uv.x >> 16));
  v[2] = bf2f((unsigned short)(uv.y & 0xffffu));
  v[3] = bf2f((unsigned short)(uv.y >> 16));
  v[4] = bf2f((unsigned short)(uv.z & 0xffffu));
  v[5] = bf2f((unsigned short)(uv.z >> 16));
  v[6] = bf2f((unsigned short)(uv.w & 0xffffu));
  v[7] = bf2f((unsigned short)(uv.w >> 16));
  float s = 0.f, s2 = 0.f;
#pragma unroll
  for (int i = 0; i < 8; i++) { s += v[i]; s2 += v[i] * v[i]; }
  for (int m = 32; m > 0; m >>= 1) {
    s += __shfl_xor(s, m, 64);
    s2 += __shfl_xor(s2, m, 64);
  }
  float mean = s * (1.0f / CDIM);
  float var = s2 * (1.0f / CDIM) - mean * mean;
  float rs = rsqrtf(var + LN_EPS);
  const float4* wr = (const float4*)w;
  const float4* br = (const float4*)b;
  float4 w0 = wr[lane * 2], w1 = wr[lane * 2 + 1];
  float4 b0 = br[lane * 2], b1 = br[lane * 2 + 1];
  unsigned int p0 = (unsigned int)f2bf((v[0] - mean) * rs * w0.x + b0.x) |
                    ((unsigned int)f2bf((v[1] - mean) * rs * w0.y + b0.y) << 16);
  unsigned int p1 = (unsigned int)f2bf((v[2] - mean) * rs * w0.z + b0.z) |
                    ((unsigned int)f2bf((v[3] - mean) * rs * w0.w + b0.w) << 16);
  unsigned int p2 = (unsigned int)f2bf((v[4] - mean) * rs * w1.x + b1.x) |
                    ((unsigned int)f2bf((v[5] - mean) * rs * w1.y + b1.y) << 16);
  unsigned int p3 = (unsigned int)f2bf((v[6] - mean) * rs * w1.z + b1.z) |
                    ((unsigned int)f2bf((v[7] - mean) * rs * w1.w + b1.w) << 16);
  uint4 pk; pk.x = p0; pk.y = p1; pk.z = p2; pk.w = p3;
  *((uint4*)(out + (size_t)row * CDIM + lane * 8)) = pk;
}

// ---------------- bf16 MFMA GEMM: C = A(MxK) * Bt(NxK)^T + epilogue --------
// 128x128 tile, 256 threads = 4 waves (2x2), per-wave 64x64 out (4x4 frags).
// BK=32. A+B via global_load_lds 2-buffer, full-drain per iter (R11 config,
// empirical optimum of 8 variants). 4 blocks/CU.
// EPI 0: n<512 -> outU = v+biasA (bf16) + fused phase1 aggregates;
//        n>=512 -> outG = sigmoid(v+biasB)
// EPI 2: outG = bf16(silu(v + biasA[n]))            (bf16 staged)
// EPI 3: outG = bf16(res_f32[idx] + v + biasA[n])   (bf16 staged; x2b)
// EPI 4: outF[idx] = bf2f(resB[idx]) + v + biasA[n] (fp32 direct; final out)
template <int EPI>
__global__ __launch_bounds__(256, 4) void gemm_bt(
    const unsigned short* __restrict__ A, const unsigned short* __restrict__ Bt,
    const float* __restrict__ biasA, const float* __restrict__ biasB,
    const float* __restrict__ res, const unsigned short* __restrict__ resB,
    float* __restrict__ outF,
    unsigned short* __restrict__ outU, unsigned short* __restrict__ outG,
    const float* __restrict__ decayP, float* __restrict__ faP,
    float* __restrict__ baP, int M, int N, int K) {
  // 34 KB shared: K-loop staging (32 KB) aliased with bf16 epilogue tile.
  __shared__ char smemRaw[34048];
  unsigned short* As = (unsigned short*)smemRaw;            // 2 bufs x 4096 elems
  unsigned short* Bs = (unsigned short*)(smemRaw + 16384);  // 2 bufs x 4096 elems

  // XCD-aware remap: grid = (M/128, N/128); XCD = bid % 8.
  int nbx = gridDim.x, nby = gridDim.y;
  int bid = blockIdx.x + blockIdx.y * nbx;
  int per = (nbx * nby) >> 3;
  int w = (bid & 7) * per + (bid >> 3);
  int ni = w % nby;
  int mi = w / nby;
  int bm = mi << 7, bn = ni << 7;

  int tid = threadIdx.x, wave = tid >> 6, lane = tid & 63;
  int wm = (wave >> 1) * 64, wn = (wave & 1) * 64;

  // staging addressing (R6-verified swizzled layout; measured 0 conflicts)
  int srow = wave * 16 + (lane >> 2);
  int chunkSel = (lane & 3) ^ ((lane >> 3) & 3);
  int scol = chunkSel * 8;
  const unsigned short* aP0 = A + (size_t)(bm + srow) * K + scol;
  const unsigned short* aP1 = A + (size_t)(bm + 64 + srow) * K + scol;
  const unsigned short* bP0 = Bt + (size_t)(bn + srow) * K + scol;
  const unsigned short* bP1 = Bt + (size_t)(bn + 64 + srow) * K + scol;
  int wbase = wave * 512; // wave-uniform LDS elem offset; HW adds lane*16B

#define STAGE(bufOff, ktile) do {                                 \
    int _o = (ktile) * 32;                                        \
    gll16(aP0 + _o, As + (bufOff) + wbase);                       \
    gll16(aP1 + _o, As + (bufOff) + 2048 + wbase);                \
    gll16(bP0 + _o, Bs + (bufOff) + wbase);                       \
    gll16(bP1 + _o, Bs + (bufOff) + 2048 + wbase);                \
  } while (0)

  floatx4 acc[4][4];
#pragma unroll
  for (int i = 0; i < 4; i++)
#pragma unroll
    for (int j = 0; j < 4; j++) acc[i][j] = (floatx4){0.f, 0.f, 0.f, 0.f};

  int quad = lane >> 4, r16 = lane & 15;
  int cSwz = ((quad ^ (r16 >> 1)) & 3) * 8; // inverse of staging swizzle

  int NK = K >> 5;

  // prologue: tile 0 -> buf0
  STAGE(0, 0);
  asm volatile("s_waitcnt vmcnt(0)" ::: "memory");
  __syncthreads();

  for (int k = 0; k < NK; ++k) {
    int cur = (k & 1) * 4096, nxt = cur ^ 4096;
    if (k + 1 < NK) STAGE(nxt, k + 1);  // prefetch next tile into other buf
    short8 af[4], bfm[4];
#pragma unroll
    for (int i = 0; i < 4; i++)
      af[i] = *(const short8*)(&As[cur + (wm + i * 16 + r16) * 32 + cSwz]);
#pragma unroll
    for (int j = 0; j < 4; j++)
      bfm[j] = *(const short8*)(&Bs[cur + (wn + j * 16 + r16) * 32 + cSwz]);
#pragma unroll
    for (int i = 0; i < 4; i++)
#pragma unroll
      for (int j = 0; j < 4; j++)
        acc[i][j] = __builtin_amdgcn_mfma_f32_16x16x32_bf16(af[i], bfm[j], acc[i][j], 0, 0, 0);
    asm volatile("s_waitcnt vmcnt(0)" ::: "memory");
    __syncthreads();
  }
#undef STAGE

  if (EPI == 4) {
    // fp32 output, bf16 residual: direct stores
#pragma unroll
    for (int j = 0; j < 4; j++) {
      int n = bn + wn + j * 16 + r16;
      float bA = biasA[n];
#pragma unroll
      for (int i = 0; i < 4; i++) {
        int mb = bm + wm + i * 16 + quad * 4;
#pragma unroll
        for (int r = 0; r < 4; r++) {
          size_t idx = (size_t)(mb + r) * N + n;
          outF[idx] = bf2f(resB[idx]) + acc[i][j][r] + bA;
        }
      }
    }
  } else {
    // bf16 output: stage tile in LDS, then coalesced 16B/lane stores
    unsigned short* sm = (unsigned short*)smemRaw;
#pragma unroll
    for (int j = 0; j < 4; j++) {
      int n = bn + wn + j * 16 + r16;
      int ln = wn + j * 16 + r16;
#pragma unroll
      for (int i = 0; i < 4; i++) {
        int lmb = wm + i * 16 + quad * 4;
#pragma unroll
        for (int r = 0; r < 4; r++) {
          float v = acc[i][j][r];
          float t;
          if (EPI == 0) {
            t = (n < 512) ? (v + biasA[n]) : sigmoidf_(v + biasB[n - 512]);
          } else if (EPI == 2) {
            float z = v + biasA[n];
            t = z * sigmoidf_(z);
          } else { // EPI == 3: x2b = res(fp32 x) + v + bias
            size_t gidx = (size_t)(bm + lmb + r) * N + n;
            t = res[gidx] + v + biasA[n];
          }
          sm[(lmb + r) * 132 + ln] = f2bf(t);
        }
      }
    }
    __syncthreads();
    int row = tid >> 1, half = tid & 1;
    const unsigned short* src = sm + row * 132 + half * 64;
    unsigned short* gptr;
    if (EPI == 0) {
      gptr = ((bn < 512) ? outU : (outG - 512)) + (size_t)(bm + row) * 512 + bn + half * 64;
    } else {
      gptr = outG + (size_t)(bm + row) * N + bn + half * 64;
    }
#pragma unroll
    for (int s = 0; s < 8; s++)
      *(short8*)(gptr + s * 8) = *(const short8*)(src + s * 8);

    // ---- fused scan_phase1 (EPI 0, u-half blocks only; R15-verified) ----
    if (EPI == 0 && bn < 512 && faP != nullptr) {
      int cl = tid & 127;          // channel within block
      int ch = tid >> 7;           // chunk half (0/1)
      int cg = bn + cl;            // global channel
      float d = decayP[cg];
      const unsigned short* col = sm + (ch * 64) * 132 + cl;
      float f = 0.f, bs = 0.f, p = 1.f;
#pragma unroll 8
      for (int t = 0; t < CHUNK; t++) {
        float v = bf2f(col[t * 132]);
        f = d * f + v;
        bs += p * v;
        p *= d;
      }
      size_t kidx = (size_t)((bm >> 6) + ch) * CDIM + cg;
      faP[kidx] = f;
      baP[kidx] = bs;
    }
  }
}

// ---------------- Scan phase 2a: group-local carries + group aggregates ----
__global__ __launch_bounds__(512) void scan_p2a(const float* __restrict__ fa,
    const float* __restrict__ ba, const float* __restrict__ decayT,
    float* __restrict__ fc, float* __restrict__ bc,
    float* __restrict__ gaF, float* __restrict__ gaB) {
  int c = threadIdx.x, g = blockIdx.x;
  float dT = decayT[c];
  int k0 = g * GCHUNK;
  float runf = 0.f;
#pragma unroll 4
  for (int j = 0; j < GCHUNK; j++) {
    size_t idx = (size_t)(k0 + j) * CDIM + c;
    fc[idx] = runf;
    runf = dT * runf + fa[idx];
  }
  gaF[(size_t)g * CDIM + c] = runf;
  float runb = 0.f;
#pragma unroll 4
  for (int j = GCHUNK - 1; j >= 0; j--) {
    size_t idx = (size_t)(k0 + j) * CDIM + c;
    bc[idx] = runb;
    runb = dT * runb + ba[idx];
  }
  gaB[(size_t)g * CDIM + c] = runb;
}

// ---------------- Scan phase 2b: 16-step group recurrence ------------------
__global__ __launch_bounds__(512) void scan_p2b(const float* __restrict__ gaF,
    const float* __restrict__ gaB, const float* __restrict__ decayT,
    float* __restrict__ GF, float* __restrict__ GB) {
  int c = threadIdx.x;
  float dT = decayT[c];
  float d32 = dT;
#pragma unroll
  for (int i = 0; i < 5; i++) d32 *= d32;  // dT^32
  float gf = 0.f;
#pragma unroll
  for (int g = 0; g < NGRP; g++) {
    GF[(size_t)g * CDIM + c] = gf;
    gf = d32 * gf + gaF[(size_t)g * CDIM + c];
  }
  float gb = 0.f;
#pragma unroll
  for (int g = NGRP - 1; g >= 0; g--) {
    GB[(size_t)g * CDIM + c] = gb;
    gb = d32 * gb + gaB[(size_t)g * CDIM + c];
  }
}

// ---------------- Scan phase 3: apply carries, combine, gate ---------------
__global__ __launch_bounds__(512) void scan_phase3(const unsigned short* __restrict__ u,
    const unsigned short* __restrict__ gate, const float* __restrict__ decay,
    const float* __restrict__ decayT, const float* __restrict__ fc,
    const float* __restrict__ bc, const float* __restrict__ GF,
    const float* __restrict__ GB, unsigned short* __restrict__ state) {
  int c = threadIdx.x, k = blockIdx.x;
  int g = k >> 5, j = k & 31;
  float d = decay[c];
  float dT = decayT[c];
  size_t base = (size_t)k * CHUNK * CDIM + c;
  size_t kc = (size_t)k * CDIM + c;
  size_t gc = (size_t)g * CDIM + c;
  float run  = fc[kc] + powi5(dT, j) * GF[gc];
  float runb0 = bc[kc] + powi5(dT, 31 - j) * GB[gc];
  float fwd[CHUNK];
  unsigned int us[CHUNK / 2];
#pragma unroll
  for (int t = 0; t < CHUNK; t++) {
    unsigned short uv = u[base + (size_t)t * CDIM];
    if (t & 1) us[t >> 1] |= ((unsigned int)uv) << 16;
    else       us[t >> 1] = uv;
    run = d * run + bf2f(uv);
    fwd[t] = run;
  }
  float runb = runb0;
#pragma unroll
  for (int t = CHUNK - 1; t >= 0; t--) {
    unsigned short uv = (unsigned short)((us[t >> 1] >> ((t & 1) * 16)) & 0xffffu);
    runb = d * runb + bf2f(uv);
    float gv = bf2f(gate[base + (size_t)t * CDIM]);
    state[base + (size_t)t * CDIM] = f2bf(0.5f * (fwd[t] + runb) * gv);
  }
}

// ---------------------------------------------------------------------------
extern "C" void kernel_launch(void* const* d_in, const int* in_sizes, int n_in,
                              void* d_out, int out_size, void* d_ws, size_t ws_size,
                              hipStream_t stream) {
  const float* x = (const float*)d_in[0];
  const float* ln1_w = (const float*)d_in[1];
  const float* ln1_b = (const float*)d_in[2];
  const float* W_in = (const float*)d_in[3];
  const float* b_in = (const float*)d_in[4];
  const float* W_gate = (const float*)d_in[5];
  const float* b_gate = (const float*)d_in[6];
  const float* W_out = (const float*)d_in[7];
  const float* b_out = (const float*)d_in[8];
  const float* decay_logit = (const float*)d_in[9];
  const float* ln2_w = (const float*)d_in[10];
  const float* ln2_b = (const float*)d_in[11];
  const float* W_ff1 = (const float*)d_in[12];
  const float* b_ff1 = (const float*)d_in[13];
  const float* W_ff2 = (const float*)d_in[14];
  const float* b_ff2 = (const float*)d_in[15];

  char* ws = (char*)d_ws;
  size_t off = 0;
  auto alloc = [&](size_t bytes) -> void* {
    void* p = ws + off;
    off += (bytes + 255) & ~(size_t)255;
    return p;
  };
  // --- small persistent buffers ---
  unsigned short* Wt_ig  = (unsigned short*)alloc((size_t)1024 * 512 * 2);
  unsigned short* Wt_out = (unsigned short*)alloc((size_t)512 * 512 * 2);
  unsigned short* Wt_ff1 = (unsigned short*)alloc((size_t)1024 * 512 * 2);
  unsigned short* Wt_ff2 = (unsigned short*)alloc((size_t)512 * 1024 * 2);
  float* fa = (float*)alloc((size_t)NCHUNK * CDIM * 4);
  float* ba = (float*)alloc((size_t)NCHUNK * CDIM * 4);
  float* fc = (float*)alloc((size_t)NCHUNK * CDIM * 4);
  float* bc = (float*)alloc((size_t)NCHUNK * CDIM * 4);
  float* gaF = (float*)alloc((size_t)NGRP * CDIM * 4);
  float* gaB = (float*)alloc((size_t)NGRP * CDIM * 4);
  float* GFb = (float*)alloc((size_t)NGRP * CDIM * 4);
  float* GBb = (float*)alloc((size_t)NGRP * CDIM * 4);
  float* decay  = (float*)alloc(CDIM * 4);
  float* decayT = (float*)alloc(CDIM * 4);
  // --- large aliased regions (liveness-disjoint) ---
  const size_t LC2 = (size_t)L_SEQ * CDIM * 2; // 33.55 MB
  unsigned short* R1 = (unsigned short*)alloc(LC2);      // hidden -> state -> hbuf
  unsigned short* R2 = (unsigned short*)alloc(LC2);      // u(bf16) -> ffb[0:]
  unsigned short* R3 = (unsigned short*)alloc(LC2);      // gate    -> ffb[L*C:]
  unsigned short* x2b = (unsigned short*)alloc(LC2);     // bf16 residual x2
  unsigned short* hidden = R1;
  unsigned short* state  = R1;
  unsigned short* hbuf   = R1;
  unsigned short* u_buf  = R2;
  unsigned short* gate   = R3;
  unsigned short* ffb    = R2; // 67 MB spanning R2+R3 (contiguous)

  // merged prep + LN1 (independent work, one launch)
  prep_ln1<<<L_SEQ / 4 + 1793, 256, 0, stream>>>(x, ln1_w, ln1_b, hidden,
      W_in, W_gate, W_out, W_ff1, W_ff2, decay_logit,
      Wt_ig, Wt_out, Wt_ff1, Wt_ff2, decay, decayT);

  // u | gate fused GEMM (N=1024) with fused phase1 aggregates
  gemm_bt<0><<<dim3(L_SEQ / 128, 1024 / 128), 256, 0, stream>>>(
      hidden, Wt_ig, b_in, b_gate, nullptr, nullptr, nullptr, u_buf, gate,
      decay, fa, ba, L_SEQ, 1024, 512);

  // bidirectional scan (hierarchical; phase1 fused above)
  scan_p2a<<<NGRP, 512, 0, stream>>>(fa, ba, decayT, fc, bc, gaF, gaB);
  scan_p2b<<<1, 512, 0, stream>>>(gaF, gaB, decayT, GFb, GBb);
  scan_phase3<<<NCHUNK, 512, 0, stream>>>(u_buf, gate, decay, decayT, fc, bc,
      GFb, GBb, state);

  // x2b = bf16(x + state @ W_out + b_out)   (bf16 residual stream)
  gemm_bt<3><<<dim3(L_SEQ / 128, 512 / 128), 256, 0, stream>>>(
      state, Wt_out, b_out, nullptr, x, nullptr, nullptr, nullptr, x2b,
      nullptr, nullptr, nullptr, L_SEQ, 512, 512);

  // LN2 (bf16 input)
  ln_bf16<<<L_SEQ / 4, 256, 0, stream>>>(x2b, ln2_w, ln2_b, hbuf);

  // ff = silu(h @ W_ff1 + b_ff1)
  gemm_bt<2><<<dim3(L_SEQ / 128, 1024 / 128), 256, 0, stream>>>(
      hbuf, Wt_ff1, b_ff1, nullptr, nullptr, nullptr, nullptr, nullptr, ffb,
      nullptr, nullptr, nullptr, L_SEQ, 1024, 512);

  // out = x2b + ff @ W_ff2 + b_ff2   (fp32, written to d_out)
  gemm_bt<4><<<dim3(L_SEQ / 128, 512 / 128), 256, 0, stream>>>(
      ffb, Wt_ff2, b_ff2, nullptr, nullptr, x2b, (float*)d_out, nullptr, nullptr,
      nullptr, nullptr, nullptr, L_SEQ, 512, 1024);
}